// Round 13
// baseline (648.532 us; speedup 1.0000x reference)
//
#include <hip/hip_runtime.h>
#include <stdint.h>

#define T_STEPS 128
#define BATCH   64
#define EMBED   256
#define HIDDEN  512
#define VOCAB   10000
#define M_ROWS  (T_STEPS*BATCH)   // 8192
#define NGATE   (4*HIDDEN)        // 2048
#define NBLK    32                // lstm worker blocks
#define NLAUNCH 256               // total cooperative blocks
#define NGEMM   (NLAUNCH-NBLK)    // 224 drafting GEMM blocks
#define NTILE_N 125               // 10000/80
#define NTILE_M 64                // 8192/128

typedef __attribute__((ext_vector_type(2))) float  f32x2;
typedef __attribute__((ext_vector_type(4))) float  f32x4;
typedef __attribute__((ext_vector_type(4))) int    i32x4;
typedef __attribute__((ext_vector_type(8))) __bf16 bf16x8;

static __device__ __forceinline__ unsigned short f32_to_bf16(float f) {
    union { float f; uint32_t u; } v; v.f = f;
    uint32_t u = v.u;
    return (unsigned short)((u + 0x7FFFu + ((u >> 16) & 1u)) >> 16);  // RNE
}
static __device__ __forceinline__ float sigf(float x) {
    return 1.f / (1.f + __expf(-x));
}
static __device__ __forceinline__ float tanhfast(float x) {
    float e = __expf(2.f * fminf(fmaxf(x, -15.f), 15.f));
    return (e - 1.f) / (e + 1.f);
}
static __device__ __forceinline__ void cell2(
    float pi0, float pi1, float pf0, float pf1, float pg0, float pg1,
    float po0, float po1, float& c0, float& c1, float& h0, float& h1) {
    float i0 = sigf(pi0), i1 = sigf(pi1);
    float f0 = sigf(pf0), f1 = sigf(pf1);
    float g0 = tanhfast(pg0), g1 = tanhfast(pg1);
    float o0 = sigf(po0), o1 = sigf(po1);
    c0 = f0 * c0 + i0 * g0;
    c1 = f1 * c1 + i1 * g1;
    h0 = o0 * tanhfast(c0);
    h1 = o1 * tanhfast(c1);
}

// IC-coherent (bypass L1+L2) primitives — the verified cross-XCD path.
static __device__ __forceinline__ i32x4 ld16ic(const void* p) {
    i32x4 r; asm volatile("global_load_dwordx4 %0, %1, off sc0 sc1" : "=v"(r) : "v"(p)); return r;
}
static __device__ __forceinline__ unsigned ld4ic(const void* p) {
    unsigned r; asm volatile("global_load_dword %0, %1, off sc0 sc1" : "=v"(r) : "v"(p)); return r;
}
static __device__ __forceinline__ void st4ic(void* p, unsigned v) {
    asm volatile("global_store_dword %0, %1, off sc0 sc1" :: "v"(p), "v"(v) : "memory");
}

// ---------------------------------------------------------------------------
// Poison hsbf (sentinel 0xFFFFFFFF) and zero flags — both via IC stores so
// no cache anywhere holds these lines (graph-replay safe).
// ---------------------------------------------------------------------------
__global__ void poison_hsbf(unsigned* __restrict__ hs, unsigned* __restrict__ fl) {
    size_t i = (size_t)blockIdx.x * 256 + threadIdx.x;   // 16B units
    if (i < 524288) {
        i32x4 v = { -1, -1, -1, -1 };
        asm volatile("global_store_dwordx4 %0, %1, off sc0 sc1"
                     :: "v"((char*)hs + i * 16), "v"(v) : "memory");
    } else if (i < 524288 + 2048) {
        i32x4 z = { 0, 0, 0, 0 };
        asm volatile("global_store_dwordx4 %0, %1, off sc0 sc1"
                     :: "v"((char*)fl + (i - 524288) * 16), "v"(z) : "memory");
    }
}

// ---------------------------------------------------------------------------
__global__ void wt_convert(const float* __restrict__ W, unsigned short* __restrict__ Wt) {
    __shared__ float tile[32][33];
    int n0 = blockIdx.x * 32;
    int k0 = blockIdx.y * 32;
    int tx = threadIdx.x, ty = threadIdx.y;
    int n = n0 + tx;
    if (n < VOCAB) tile[ty][tx] = W[(size_t)(k0 + ty) * VOCAB + n];
    __syncthreads();
    int nn = n0 + ty;
    if (nn < VOCAB) Wt[(size_t)nn * HIDDEN + k0 + tx] = f32_to_bf16(tile[tx][ty]);
}

// ---------------------------------------------------------------------------
__global__ void wh_convert(const float* __restrict__ Whi, const float* __restrict__ Whf,
                           const float* __restrict__ Whc, const float* __restrict__ Who,
                           unsigned short* __restrict__ WhT) {
    __shared__ float tile[32][33];
    int g = blockIdx.z;
    const float* Wg = (g == 0) ? Whi : (g == 1) ? Whf : (g == 2) ? Whc : Who;
    int n0 = blockIdx.x * 32, k0 = blockIdx.y * 32;
    int tx = threadIdx.x, ty = threadIdx.y;
    tile[ty][tx] = Wg[(size_t)(k0 + ty) * HIDDEN + n0 + tx];
    __syncthreads();
    WhT[((size_t)g * HIDDEN + n0 + ty) * HIDDEN + k0 + tx] = f32_to_bf16(tile[tx][ty]);
}

// ---------------------------------------------------------------------------
// Emb [10000][256] f32 -> bf16 (elementwise)
// ---------------------------------------------------------------------------
__global__ void emb_convert(const float* __restrict__ E, unsigned short* __restrict__ Eb) {
    size_t i = ((size_t)blockIdx.x * 256 + threadIdx.x) * 4;
    if (i >= (size_t)VOCAB * EMBED) return;
    f32x4 v = *reinterpret_cast<const f32x4*>(E + i);
    unsigned short o[4];
    #pragma unroll
    for (int j = 0; j < 4; ++j) o[j] = f32_to_bf16(v[j]);
    *reinterpret_cast<unsigned long long*>(Eb + i) =
        ((unsigned long long)o[3] << 48) | ((unsigned long long)o[2] << 32) |
        ((unsigned long long)o[1] << 16) | (unsigned long long)o[0];
}

// ---------------------------------------------------------------------------
// Wx_g [256 k][512 n] f32 -> WxT [2048 n][256 k] bf16
// ---------------------------------------------------------------------------
__global__ void wx_convert(const float* __restrict__ Wxi, const float* __restrict__ Wxf,
                           const float* __restrict__ Wxc, const float* __restrict__ Wxo,
                           unsigned short* __restrict__ WxT) {
    __shared__ float tile[32][33];
    int g = blockIdx.z;
    const float* Wg = (g == 0) ? Wxi : (g == 1) ? Wxf : (g == 2) ? Wxc : Wxo;
    int n0 = blockIdx.x * 32, k0 = blockIdx.y * 32;   // n<512, k<256
    int tx = threadIdx.x, ty = threadIdx.y;
    tile[ty][tx] = Wg[(size_t)(k0 + ty) * HIDDEN + n0 + tx];
    __syncthreads();
    WxT[((size_t)g * HIDDEN + n0 + ty) * EMBED + k0 + tx] = f32_to_bf16(tile[tx][ty]);
}

// ---------------------------------------------------------------------------
// xg[m][c] = embeds_bf16[m,:] @ WxT[c,:]^T + b   (bf16 MFMA, f32 out)
// BM=128 BN=64 BK=64, 256 thr / 4 waves, acc[2][4]. grid (32, 64).
// ---------------------------------------------------------------------------
__global__ __launch_bounds__(256) void xproj_mfma(
    const int* __restrict__ idx, const unsigned short* __restrict__ Eb,
    const unsigned short* __restrict__ WxT,
    const float* __restrict__ bi,  const float* __restrict__ bf_,
    const float* __restrict__ bc,  const float* __restrict__ bo,
    float* __restrict__ xg)
{
    __shared__ __align__(16) char sA[128 * 128];  // 128 rows x 64 bf16
    __shared__ __align__(16) char sB[64 * 128];   // 64 rows x 64 bf16
    int n0 = blockIdx.x * 64;
    int m0 = blockIdx.y * 128;
    int tid = threadIdx.x;
    int w = tid >> 6, lane = tid & 63;
    f32x4 acc[2][4] = {};

    int arow[4], aer[4];
    #pragma unroll
    for (int i = 0; i < 4; ++i) {
        int s = tid + i * 256;
        arow[i] = s >> 3;
        aer[i]  = idx[m0 + arow[i]];
    }

    for (int kc = 0; kc < 4; ++kc) {
        int k0 = kc * 64;
        #pragma unroll
        for (int i = 0; i < 4; ++i) {                  // A: 1024 16B slots
            int s = tid + i * 256;
            int row = arow[i], slot = s & 7;
            i32x4 v = *reinterpret_cast<const i32x4*>(Eb + (size_t)aer[i] * EMBED + k0 + slot * 8);
            *reinterpret_cast<i32x4*>(sA + row * 128 + ((slot ^ (row & 7)) * 16)) = v;
        }
        #pragma unroll
        for (int i = 0; i < 2; ++i) {                  // B: 512 slots
            int s = tid + i * 256;
            int row = s >> 3, slot = s & 7;
            i32x4 v = *reinterpret_cast<const i32x4*>(WxT + (size_t)(n0 + row) * EMBED + k0 + slot * 8);
            *reinterpret_cast<i32x4*>(sB + row * 128 + ((slot ^ (row & 7)) * 16)) = v;
        }
        __syncthreads();
        #pragma unroll
        for (int k2 = 0; k2 < 2; ++k2) {
            bf16x8 a[2], b[4];
            #pragma unroll
            for (int rf = 0; rf < 2; ++rf) {
                int row = w * 32 + rf * 16 + (lane & 15);
                int off = (k2 * 64 + (lane >> 4) * 16) ^ ((row & 7) << 4);
                a[rf] = *reinterpret_cast<const bf16x8*>(sA + row * 128 + off);
            }
            #pragma unroll
            for (int cf = 0; cf < 4; ++cf) {
                int row = cf * 16 + (lane & 15);
                int off = (k2 * 64 + (lane >> 4) * 16) ^ ((row & 7) << 4);
                b[cf] = *reinterpret_cast<const bf16x8*>(sB + row * 128 + off);
            }
            #pragma unroll
            for (int rf = 0; rf < 2; ++rf)
                #pragma unroll
                for (int cf = 0; cf < 4; ++cf)
                    acc[rf][cf] = __builtin_amdgcn_mfma_f32_16x16x32_bf16(a[rf], b[cf], acc[rf][cf], 0, 0, 0);
        }
        __syncthreads();
    }
    #pragma unroll
    for (int cf = 0; cf < 4; ++cf) {
        int col = n0 + cf * 16 + (lane & 15);          // 0..2047
        int g = col >> 9, hc = col & 511;
        const float* bg = (g == 0) ? bi : (g == 1) ? bf_ : (g == 2) ? bc : bo;
        float bv = bg[hc];
        #pragma unroll
        for (int rf = 0; rf < 2; ++rf)
            #pragma unroll
            for (int r = 0; r < 4; ++r) {
                int row = m0 + w * 32 + rf * 16 + (lane >> 4) * 4 + r;
                xg[(size_t)row * NGATE + col] = acc[rf][cf][r] + bv;
            }
    }
}

// ---------------------------------------------------------------------------
// FUSED persistent kernel, 256 blocks x 512 threads (cooperative):
//  blocks 0..31   : R8 batch-split double-pipeline LSTM scan + READY FLAGS.
//  blocks 32..255 : out_proj GEMM drafting behind the scan (flag-gated,
//                   cached A/B loads). C epilogue COALESCED via LDS bounce:
//                   stage 128x80 f32 tile (+bias) in smem, write 320B/row
//                   contiguous dwordx4 bursts (full-line writes -> no
//                   write-allocate reads of C).
// ---------------------------------------------------------------------------
__global__ __launch_bounds__(512) void lstm_fused(
    const float* __restrict__ xg,
    const unsigned short* __restrict__ WhT,   // [4][512][512] bf16
    unsigned short* hsbf,                     // [128][64][512] bf16 (poisoned)
    float* __restrict__ hfin, float* __restrict__ cfin,
    const unsigned short* __restrict__ Btbf,  // [10000][512] bf16
    const float* __restrict__ bias,           // [10000]
    float* __restrict__ Cout,                 // [8192][10000] f32
    unsigned* flags)                          // [128 t][2 G][32 bx] (pre-zeroed)
{
    __shared__ __align__(16) unsigned char smem[41472];
    const int tid = threadIdx.x;

    if (blockIdx.x < NBLK) {
        // =================== SCAN ROLE (R8 + flags) ========================
        unsigned char* hstage = smem;                               // 32KB
        auto P_lds = reinterpret_cast<float (*)[32][17]>(smem + 32768);
        const int bx   = blockIdx.x;
        const int hc0  = bx * 16;
        const int lane = tid & 63, w = tid >> 6;
        const int wm   = w >> 2, wg = w & 3;

        bf16x8 breg[16];
        {
            const unsigned short* base =
                WhT + ((size_t)wg * HIDDEN + hc0 + (lane & 15)) * HIDDEN + (lane >> 4) * 8;
            #pragma unroll
            for (int ks = 0; ks < 16; ++ks)
                breg[ks] = *reinterpret_cast<const bf16x8*>(base + ks * 32);
        }

        const int ub  = tid >> 3;          // 0..31 (tid<256)
        const int uhp = tid & 7;
        const int uhc = hc0 + uhp * 2;
        float cA0 = 0.f, cA1 = 0.f, cB0 = 0.f, cB1 = 0.f;
        f32x2 xvA[4], xvB[4];
        if (tid < 256) {
            const float* xrA = xg + (size_t)(0 * 32 + ub) * NGATE + uhc;
            const float* xrB = xg + (size_t)(1 * 32 + ub) * NGATE + uhc;
            #pragma unroll
            for (int g = 0; g < 4; ++g) {
                xvA[g] = *reinterpret_cast<const f32x2*>(xrA + g * HIDDEN);
                xvB[g] = *reinterpret_cast<const f32x2*>(xrB + g * HIDDEN);
            }
        }
        unsigned* hs32 = reinterpret_cast<unsigned*>(hsbf);

#define CHK(R) { mx = (mx > (unsigned)R[0]) ? mx : (unsigned)R[0]; \
                 mx = (mx > (unsigned)R[1]) ? mx : (unsigned)R[1]; \
                 mx = (mx > (unsigned)R[2]) ? mx : (unsigned)R[2]; \
                 mx = (mx > (unsigned)R[3]) ? mx : (unsigned)R[3]; }
#define STLDS(R, I) { int s16 = (I) * 512 + tid; int row = s16 >> 6, sl = s16 & 63; \
        *reinterpret_cast<i32x4*>(hstage + row * 1024 + ((sl ^ (row & 7)) << 4)) = R; }

#define GROUP_UPDATE(G, XV, C0, C1, TT)                                         \
    if (tid < 256) {                                                            \
        int hp2 = uhp * 2;                                                      \
        float h0, h1;                                                           \
        cell2(P_lds[0][ub][hp2] + XV[0][0], P_lds[0][ub][hp2+1] + XV[0][1],     \
              P_lds[1][ub][hp2] + XV[1][0], P_lds[1][ub][hp2+1] + XV[1][1],     \
              P_lds[2][ub][hp2] + XV[2][0], P_lds[2][ub][hp2+1] + XV[2][1],     \
              P_lds[3][ub][hp2] + XV[3][0], P_lds[3][ub][hp2+1] + XV[3][1],     \
              C0, C1, h0, h1);                                                  \
        unsigned hp = ((unsigned)f32_to_bf16(h1) << 16) | (unsigned)f32_to_bf16(h0); \
        st4ic(hs32 + (size_t)(TT) * 16384 + ((G) * 32 + ub) * 256 + (uhc >> 1), hp); \
        if ((TT) == T_STEPS - 1) {                                              \
            f32x2 hv = { h0, h1 };                                              \
            *reinterpret_cast<f32x2*>(hfin + (size_t)((G) * 32 + ub) * HIDDEN + uhc) = hv; \
            f32x2 cv = { C0, C1 };                                              \
            *reinterpret_cast<f32x2*>(cfin + (size_t)((G) * 32 + ub) * HIDDEN + uhc) = cv; \
        } else {                                                                \
            const float* xr = xg + (size_t)(((TT) + 1) * BATCH + (G) * 32 + ub) * NGATE + uhc; \
            _Pragma("unroll")                                                   \
            for (int g = 0; g < 4; ++g)                                         \
                XV[g] = *reinterpret_cast<const f32x2*>(xr + g * HIDDEN);       \
        }                                                                       \
    }

#define GROUP_PHASE(G, XV, C0, C1, TT)                                          \
    {                                                                           \
        f32x4 acc = {0.f, 0.f, 0.f, 0.f};                                       \
        {                                                                       \
            const char* hb = (const char*)hsbf + (size_t)((TT) - 1) * 65536 + (G) * 32768; \
            i32x4 q0, q1, q2, q3;                                               \
            for (int rnd = 0; rnd < (1 << 16); ++rnd) {                         \
                q0 = ld16ic(hb + (size_t)(0 * 512 + tid) * 16);                 \
                q1 = ld16ic(hb + (size_t)(1 * 512 + tid) * 16);                 \
                q2 = ld16ic(hb + (size_t)(2 * 512 + tid) * 16);                 \
                q3 = ld16ic(hb + (size_t)(3 * 512 + tid) * 16);                 \
                asm volatile("s_waitcnt vmcnt(0)"                               \
                    : "+v"(q0), "+v"(q1), "+v"(q2), "+v"(q3));                  \
                unsigned mx = 0u;                                               \
                CHK(q0) CHK(q1) CHK(q2) CHK(q3)                                 \
                if (mx != 0xFFFFFFFFu) break;                                   \
                __builtin_amdgcn_s_sleep(1);                                    \
            }                                                                   \
            __builtin_amdgcn_sched_barrier(0);                                  \
            STLDS(q0, 0) STLDS(q1, 1) STLDS(q2, 2) STLDS(q3, 3)                 \
        }                                                                       \
        __syncthreads();   /* implied vmcnt(0): prev slot's publishes ACKed */  \
        if (tid == 0) {                                                         \
            int s_ = 2 * (TT) + (G);                                            \
            int ps = s_ - 1;                                                    \
            st4ic(flags + ((size_t)(ps >> 1) * 64 + (ps & 1) * 32 + bx), 1u);   \
            if (s_ == 2) st4ic(flags + bx, 1u);   /* slot 0 = (A,0) */          \
        }                                                                       \
        {                                                                       \
            const int rr = wm * 16 + (lane & 15);                               \
            _Pragma("unroll")                                                   \
            for (int ks = 0; ks < 16; ++ks) {                                   \
                int sl = ks * 4 + (lane >> 4);                                  \
                bf16x8 a = *reinterpret_cast<const bf16x8*>(                    \
                    hstage + rr * 1024 + ((sl ^ (rr & 7)) << 4));               \
                acc = __builtin_amdgcn_mfma_f32_16x16x32_bf16(a, breg[ks], acc, 0, 0, 0); \
            }                                                                   \
        }                                                                       \
        {                                                                       \
            int colr = lane & 15, rowb = (lane >> 4) * 4;                       \
            _Pragma("unroll")                                                   \
            for (int r = 0; r < 4; ++r)                                         \
                P_lds[wg][wm * 16 + rowb + r][colr] = acc[r];                   \
        }                                                                       \
        __syncthreads();                                                        \
        GROUP_UPDATE(G, XV, C0, C1, TT)                                         \
    }

        // t = 0: registers only
        if (tid < 256) {
            float h0, h1;
            cell2(xvA[0][0], xvA[0][1], xvA[1][0], xvA[1][1],
                  xvA[2][0], xvA[2][1], xvA[3][0], xvA[3][1], cA0, cA1, h0, h1);
            unsigned hp = ((unsigned)f32_to_bf16(h1) << 16) | (unsigned)f32_to_bf16(h0);
            st4ic(hs32 + (size_t)(0 * 32 + ub) * 256 + (uhc >> 1), hp);
            const float* xr = xg + (size_t)(1 * BATCH + 0 * 32 + ub) * NGATE + uhc;
            #pragma unroll
            for (int g = 0; g < 4; ++g)
                xvA[g] = *reinterpret_cast<const f32x2*>(xr + g * HIDDEN);

            cell2(xvB[0][0], xvB[0][1], xvB[1][0], xvB[1][1],
                  xvB[2][0], xvB[2][1], xvB[3][0], xvB[3][1], cB0, cB1, h0, h1);
            hp = ((unsigned)f32_to_bf16(h1) << 16) | (unsigned)f32_to_bf16(h0);
            st4ic(hs32 + (size_t)(1 * 32 + ub) * 256 + (uhc >> 1), hp);
            xr = xg + (size_t)(1 * BATCH + 1 * 32 + ub) * NGATE + uhc;
            #pragma unroll
            for (int g = 0; g < 4; ++g)
                xvB[g] = *reinterpret_cast<const f32x2*>(xr + g * HIDDEN);
        }

        for (int t = 1; t < T_STEPS; ++t) {
            GROUP_PHASE(0, xvA, cA0, cA1, t)
            GROUP_PHASE(1, xvB, cB0, cB1, t)
        }
#undef GROUP_PHASE
#undef GROUP_UPDATE
#undef STLDS
#undef CHK
        // final slot (B,127): drain, then fire its flag
        __syncthreads();
        if (tid == 0)
            st4ic(flags + ((size_t)127 * 64 + 32 + bx), 1u);
    } else {
        // =================== DRAFTING GEMM ROLE ============================
        char* sA = (char*)smem;            // 128 rows x 128B = 16KB
        char* sB = (char*)smem + 16384;    // 80 rows x 128B  = 10KB
        float* sC = (float*)smem;          // epilogue reuse: 128 x 80 f32 = 40KB
        const int gbid = blockIdx.x - NBLK;     // 0..223
        const int w = tid >> 6, lane = tid & 63;
        const unsigned short* __restrict__ Abf = hsbf;   // read-only here

        for (int L = gbid; L < NTILE_M * NTILE_N; L += NGEMM) {
            int mi = L / NTILE_N, ni = L - mi * NTILE_N;
            int m0 = mi * 128, n0 = ni * 80;
            // ---- flag gate: 128 dwords (t = 2mi, 2mi+1; both groups, 32 blks)
            {
                const unsigned* fl = flags + (size_t)2 * mi * 64;
                for (int rnd = 0; rnd < (1 << 20); ++rnd) {
                    unsigned v = 1u;
                    if (tid < 128) v = ld4ic(fl + tid);
                    asm volatile("s_waitcnt vmcnt(0)" : "+v"(v));
                    int bad = (tid < 128) && (v == 0u);
                    if (__syncthreads_count(bad) == 0) break;
                    __builtin_amdgcn_s_sleep(16);
                }
                asm volatile("" ::: "memory");   // keep A loads below the gate
            }
            f32x4 acc[5] = {};
            for (int kc = 0; kc < 8; ++kc) {
                int k0 = kc * 64;
                #pragma unroll
                for (int i = 0; i < 2; ++i) {          // A: 1024 slots, cached
                    int s = tid + i * 512;
                    int row = s >> 3, slot = s & 7;
                    i32x4 v = *reinterpret_cast<const i32x4*>(
                        Abf + (size_t)(m0 + row) * HIDDEN + k0 + slot * 8);
                    *reinterpret_cast<i32x4*>(sA + row * 128 + ((slot ^ (row & 7)) * 16)) = v;
                }
                {                                      // B: 640 slots, cached
                    int s = tid, br = s >> 3, bs = s & 7;
                    i32x4 v = *reinterpret_cast<const i32x4*>(
                        Btbf + (size_t)(n0 + br) * HIDDEN + k0 + bs * 8);
                    *reinterpret_cast<i32x4*>(sB + br * 128 + ((bs ^ (br & 7)) * 16)) = v;
                    if (tid < 128) {
                        s = 512 + tid; br = s >> 3; bs = s & 7;
                        v = *reinterpret_cast<const i32x4*>(
                            Btbf + (size_t)(n0 + br) * HIDDEN + k0 + bs * 8);
                        *reinterpret_cast<i32x4*>(sB + br * 128 + ((bs ^ (br & 7)) * 16)) = v;
                    }
                }
                __syncthreads();
                #pragma unroll
                for (int k2 = 0; k2 < 2; ++k2) {
                    int arow = w * 16 + (lane & 15);
                    int aoff = (k2 * 64 + (lane >> 4) * 16) ^ ((arow & 7) << 4);
                    bf16x8 a = *reinterpret_cast<const bf16x8*>(sA + arow * 128 + aoff);
                    #pragma unroll
                    for (int cf = 0; cf < 5; ++cf) {
                        int brow = cf * 16 + (lane & 15);
                        int boff = (k2 * 64 + (lane >> 4) * 16) ^ ((brow & 7) << 4);
                        bf16x8 b = *reinterpret_cast<const bf16x8*>(sB + brow * 128 + boff);
                        acc[cf] = __builtin_amdgcn_mfma_f32_16x16x32_bf16(a, b, acc[cf], 0, 0, 0);
                    }
                }
                __syncthreads();
            }
            // -------- epilogue: LDS bounce -> coalesced 320B-per-row bursts
            #pragma unroll
            for (int cf = 0; cf < 5; ++cf) {
                int col = cf * 16 + (lane & 15);
                float bv = bias[n0 + col];
                #pragma unroll
                for (int r = 0; r < 4; ++r) {
                    int row = w * 16 + (lane >> 4) * 4 + r;
                    sC[row * 80 + col] = acc[cf][r] + bv;
                }
            }
            __syncthreads();
            #pragma unroll
            for (int i = 0; i < 5; ++i) {              // 2560 f32x4 units
                int u = tid + i * 512;
                int row = u / 20, c4 = u % 20;
                f32x4 v = *reinterpret_cast<const f32x4*>(sC + row * 80 + c4 * 4);
                *reinterpret_cast<f32x4*>(Cout + (size_t)(m0 + row) * VOCAB + n0 + c4 * 4) = v;
            }
            __syncthreads();                           // sC free before next tile
        }
    }
}

// ---------------------------------------------------------------------------
__global__ void finalize_hc(const float* __restrict__ hfin, const float* __restrict__ cfin,
                            float* __restrict__ out) {
    int i = blockIdx.x * 256 + threadIdx.x;       // 0..65535
    size_t base = (size_t)M_ROWS * VOCAB;
    if (i < BATCH * HIDDEN)
        out[base + i] = hfin[i];
    else
        out[base + i] = cfin[i - BATCH * HIDDEN];
}

extern "C" void kernel_launch(void* const* d_in, const int* in_sizes, int n_in,
                              void* d_out, int out_size, void* d_ws, size_t ws_size,
                              hipStream_t stream) {
    (void)in_sizes; (void)n_in; (void)out_size; (void)ws_size;
    const int*   input_ = (const int*)  d_in[0];
    const float* Emb    = (const float*)d_in[1];
    const float* Wxi    = (const float*)d_in[2];
    const float* Whi    = (const float*)d_in[3];
    const float* bi     = (const float*)d_in[4];
    const float* Wxf    = (const float*)d_in[5];
    const float* Whf    = (const float*)d_in[6];
    const float* bf_    = (const float*)d_in[7];
    const float* Wxc    = (const float*)d_in[8];
    const float* Whc    = (const float*)d_in[9];
    const float* bc     = (const float*)d_in[10];
    const float* Wxo    = (const float*)d_in[11];
    const float* Who    = (const float*)d_in[12];
    const float* bo     = (const float*)d_in[13];
    const float* W      = (const float*)d_in[14];
    const float* b      = (const float*)d_in[15];
    float* out = (float*)d_out;

    char* ws = (char*)d_ws;
    float*          xg   = (float*)         (ws);                 // 67,108,864
    unsigned short* hsbf = (unsigned short*)(ws +  67108864);     //  8,388,608
    unsigned short* Wtbf = (unsigned short*)(ws +  75497472);     // 10,240,000
    unsigned short* WhT  = (unsigned short*)(ws +  85737472);     //  2,097,152
    unsigned short* Embb = (unsigned short*)(ws +  87834624);     //  5,120,000
    unsigned short* WxT  = (unsigned short*)(ws +  92954624);     //  1,048,576
    float*          hfin = (float*)         (ws +  94003200);     //    131,072
    float*          cbuf = (float*)         (ws +  94134272);     //    131,072
    unsigned*       flags= (unsigned*)      (ws +  94265344);     //     32,768

    poison_hsbf<<<2057, 256, 0, stream>>>((unsigned*)hsbf, flags);
    wt_convert<<<dim3(313, 16), dim3(32, 32), 0, stream>>>(W, Wtbf);
    wh_convert<<<dim3(16, 16, 4), dim3(32, 32), 0, stream>>>(Whi, Whf, Whc, Who, WhT);
    emb_convert<<<2500, 256, 0, stream>>>(Emb, Embb);
    wx_convert<<<dim3(16, 8, 4), dim3(32, 32), 0, stream>>>(Wxi, Wxf, Wxc, Wxo, WxT);
    xproj_mfma<<<dim3(32, 64), 256, 0, stream>>>(input_, Embb, WxT, bi, bf_, bc, bo, xg);

    {
        const float* xg_c = xg;
        const unsigned short* WhT_c = WhT;
        unsigned short* hsbf_p = hsbf;
        float* hfin_p = hfin; float* cbuf_p = cbuf;
        const unsigned short* Wtbf_c = Wtbf;
        const float* b_c = b;
        float* out_p = out;
        unsigned* flags_p = flags;
        void* args[] = { (void*)&xg_c, (void*)&WhT_c, (void*)&hsbf_p,
                         (void*)&hfin_p, (void*)&cbuf_p,
                         (void*)&Wtbf_c, (void*)&b_c, (void*)&out_p, (void*)&flags_p };
        hipLaunchCooperativeKernel((void*)lstm_fused, dim3(NLAUNCH), dim3(512), args, 0, stream);
    }

    finalize_hc<<<256, 256, 0, stream>>>(hfin, cbuf, out);
}

// Round 14
// 615.468 us; speedup vs baseline: 1.0537x; 1.0537x over previous
//
#include <hip/hip_runtime.h>
#include <stdint.h>

#define T_STEPS 128
#define BATCH   64
#define EMBED   256
#define HIDDEN  512
#define VOCAB   10000
#define M_ROWS  (T_STEPS*BATCH)   // 8192
#define NGATE   (4*HIDDEN)        // 2048
#define NBLK    32                // lstm worker blocks
#define NLAUNCH 256               // total cooperative blocks
#define NGEMM   (NLAUNCH-NBLK)    // 224 drafting GEMM blocks
#define NTILE_N 125               // 10000/80
#define NTILE_M 64                // 8192/128

typedef __attribute__((ext_vector_type(2))) float  f32x2;
typedef __attribute__((ext_vector_type(4))) float  f32x4;
typedef __attribute__((ext_vector_type(4))) int    i32x4;
typedef __attribute__((ext_vector_type(8))) __bf16 bf16x8;

static __device__ __forceinline__ unsigned short f32_to_bf16(float f) {
    union { float f; uint32_t u; } v; v.f = f;
    uint32_t u = v.u;
    return (unsigned short)((u + 0x7FFFu + ((u >> 16) & 1u)) >> 16);  // RNE
}
static __device__ __forceinline__ float sigf(float x) {
    return 1.f / (1.f + __expf(-x));
}
static __device__ __forceinline__ float tanhfast(float x) {
    float e = __expf(2.f * fminf(fmaxf(x, -15.f), 15.f));
    return (e - 1.f) / (e + 1.f);
}
static __device__ __forceinline__ void cell2(
    float pi0, float pi1, float pf0, float pf1, float pg0, float pg1,
    float po0, float po1, float& c0, float& c1, float& h0, float& h1) {
    float i0 = sigf(pi0), i1 = sigf(pi1);
    float f0 = sigf(pf0), f1 = sigf(pf1);
    float g0 = tanhfast(pg0), g1 = tanhfast(pg1);
    float o0 = sigf(po0), o1 = sigf(po1);
    c0 = f0 * c0 + i0 * g0;
    c1 = f1 * c1 + i1 * g1;
    h0 = o0 * tanhfast(c0);
    h1 = o1 * tanhfast(c1);
}

// IC-coherent (bypass L1+L2) primitives — the verified cross-XCD path.
static __device__ __forceinline__ i32x4 ld16ic(const void* p) {
    i32x4 r; asm volatile("global_load_dwordx4 %0, %1, off sc0 sc1" : "=v"(r) : "v"(p)); return r;
}
static __device__ __forceinline__ unsigned ld4ic(const void* p) {
    unsigned r; asm volatile("global_load_dword %0, %1, off sc0 sc1" : "=v"(r) : "v"(p)); return r;
}
static __device__ __forceinline__ void st4ic(void* p, unsigned v) {
    asm volatile("global_store_dword %0, %1, off sc0 sc1" :: "v"(p), "v"(v) : "memory");
}

// ---------------------------------------------------------------------------
// Poison hsbf (sentinel 0xFFFFFFFF) and zero flags — both via IC stores so
// no cache anywhere holds these lines (graph-replay safe).
// ---------------------------------------------------------------------------
__global__ void poison_hsbf(unsigned* __restrict__ hs, unsigned* __restrict__ fl) {
    size_t i = (size_t)blockIdx.x * 256 + threadIdx.x;   // 16B units
    if (i < 524288) {
        i32x4 v = { -1, -1, -1, -1 };
        asm volatile("global_store_dwordx4 %0, %1, off sc0 sc1"
                     :: "v"((char*)hs + i * 16), "v"(v) : "memory");
    } else if (i < 524288 + 2048) {
        i32x4 z = { 0, 0, 0, 0 };
        asm volatile("global_store_dwordx4 %0, %1, off sc0 sc1"
                     :: "v"((char*)fl + (i - 524288) * 16), "v"(z) : "memory");
    }
}

// ---------------------------------------------------------------------------
__global__ void wt_convert(const float* __restrict__ W, unsigned short* __restrict__ Wt) {
    __shared__ float tile[32][33];
    int n0 = blockIdx.x * 32;
    int k0 = blockIdx.y * 32;
    int tx = threadIdx.x, ty = threadIdx.y;
    int n = n0 + tx;
    if (n < VOCAB) tile[ty][tx] = W[(size_t)(k0 + ty) * VOCAB + n];
    __syncthreads();
    int nn = n0 + ty;
    if (nn < VOCAB) Wt[(size_t)nn * HIDDEN + k0 + tx] = f32_to_bf16(tile[tx][ty]);
}

// ---------------------------------------------------------------------------
__global__ void wh_convert(const float* __restrict__ Whi, const float* __restrict__ Whf,
                           const float* __restrict__ Whc, const float* __restrict__ Who,
                           unsigned short* __restrict__ WhT) {
    __shared__ float tile[32][33];
    int g = blockIdx.z;
    const float* Wg = (g == 0) ? Whi : (g == 1) ? Whf : (g == 2) ? Whc : Who;
    int n0 = blockIdx.x * 32, k0 = blockIdx.y * 32;
    int tx = threadIdx.x, ty = threadIdx.y;
    tile[ty][tx] = Wg[(size_t)(k0 + ty) * HIDDEN + n0 + tx];
    __syncthreads();
    WhT[((size_t)g * HIDDEN + n0 + ty) * HIDDEN + k0 + tx] = f32_to_bf16(tile[tx][ty]);
}

// ---------------------------------------------------------------------------
// Emb [10000][256] f32 -> bf16 (elementwise)
// ---------------------------------------------------------------------------
__global__ void emb_convert(const float* __restrict__ E, unsigned short* __restrict__ Eb) {
    size_t i = ((size_t)blockIdx.x * 256 + threadIdx.x) * 4;
    if (i >= (size_t)VOCAB * EMBED) return;
    f32x4 v = *reinterpret_cast<const f32x4*>(E + i);
    unsigned short o[4];
    #pragma unroll
    for (int j = 0; j < 4; ++j) o[j] = f32_to_bf16(v[j]);
    *reinterpret_cast<unsigned long long*>(Eb + i) =
        ((unsigned long long)o[3] << 48) | ((unsigned long long)o[2] << 32) |
        ((unsigned long long)o[1] << 16) | (unsigned long long)o[0];
}

// ---------------------------------------------------------------------------
// Wx_g [256 k][512 n] f32 -> WxT [2048 n][256 k] bf16
// ---------------------------------------------------------------------------
__global__ void wx_convert(const float* __restrict__ Wxi, const float* __restrict__ Wxf,
                           const float* __restrict__ Wxc, const float* __restrict__ Wxo,
                           unsigned short* __restrict__ WxT) {
    __shared__ float tile[32][33];
    int g = blockIdx.z;
    const float* Wg = (g == 0) ? Wxi : (g == 1) ? Wxf : (g == 2) ? Wxc : Wxo;
    int n0 = blockIdx.x * 32, k0 = blockIdx.y * 32;   // n<512, k<256
    int tx = threadIdx.x, ty = threadIdx.y;
    tile[ty][tx] = Wg[(size_t)(k0 + ty) * HIDDEN + n0 + tx];
    __syncthreads();
    WxT[((size_t)g * HIDDEN + n0 + ty) * EMBED + k0 + tx] = f32_to_bf16(tile[tx][ty]);
}

// ---------------------------------------------------------------------------
// xg[m][c] = embeds_bf16[m,:] @ WxT[c,:]^T + b   (bf16 MFMA, f32 out)
// BM=128 BN=64 BK=64, 256 thr / 4 waves, acc[2][4]. grid (32, 64).
// ---------------------------------------------------------------------------
__global__ __launch_bounds__(256) void xproj_mfma(
    const int* __restrict__ idx, const unsigned short* __restrict__ Eb,
    const unsigned short* __restrict__ WxT,
    const float* __restrict__ bi,  const float* __restrict__ bf_,
    const float* __restrict__ bc,  const float* __restrict__ bo,
    float* __restrict__ xg)
{
    __shared__ __align__(16) char sA[128 * 128];  // 128 rows x 64 bf16
    __shared__ __align__(16) char sB[64 * 128];   // 64 rows x 64 bf16
    int n0 = blockIdx.x * 64;
    int m0 = blockIdx.y * 128;
    int tid = threadIdx.x;
    int w = tid >> 6, lane = tid & 63;
    f32x4 acc[2][4] = {};

    int arow[4], aer[4];
    #pragma unroll
    for (int i = 0; i < 4; ++i) {
        int s = tid + i * 256;
        arow[i] = s >> 3;
        aer[i]  = idx[m0 + arow[i]];
    }

    for (int kc = 0; kc < 4; ++kc) {
        int k0 = kc * 64;
        #pragma unroll
        for (int i = 0; i < 4; ++i) {                  // A: 1024 16B slots
            int s = tid + i * 256;
            int row = arow[i], slot = s & 7;
            i32x4 v = *reinterpret_cast<const i32x4*>(Eb + (size_t)aer[i] * EMBED + k0 + slot * 8);
            *reinterpret_cast<i32x4*>(sA + row * 128 + ((slot ^ (row & 7)) * 16)) = v;
        }
        #pragma unroll
        for (int i = 0; i < 2; ++i) {                  // B: 512 slots
            int s = tid + i * 256;
            int row = s >> 3, slot = s & 7;
            i32x4 v = *reinterpret_cast<const i32x4*>(WxT + (size_t)(n0 + row) * EMBED + k0 + slot * 8);
            *reinterpret_cast<i32x4*>(sB + row * 128 + ((slot ^ (row & 7)) * 16)) = v;
        }
        __syncthreads();
        #pragma unroll
        for (int k2 = 0; k2 < 2; ++k2) {
            bf16x8 a[2], b[4];
            #pragma unroll
            for (int rf = 0; rf < 2; ++rf) {
                int row = w * 32 + rf * 16 + (lane & 15);
                int off = (k2 * 64 + (lane >> 4) * 16) ^ ((row & 7) << 4);
                a[rf] = *reinterpret_cast<const bf16x8*>(sA + row * 128 + off);
            }
            #pragma unroll
            for (int cf = 0; cf < 4; ++cf) {
                int row = cf * 16 + (lane & 15);
                int off = (k2 * 64 + (lane >> 4) * 16) ^ ((row & 7) << 4);
                b[cf] = *reinterpret_cast<const bf16x8*>(sB + row * 128 + off);
            }
            #pragma unroll
            for (int rf = 0; rf < 2; ++rf)
                #pragma unroll
                for (int cf = 0; cf < 4; ++cf)
                    acc[rf][cf] = __builtin_amdgcn_mfma_f32_16x16x32_bf16(a[rf], b[cf], acc[rf][cf], 0, 0, 0);
        }
        __syncthreads();
    }
    #pragma unroll
    for (int cf = 0; cf < 4; ++cf) {
        int col = n0 + cf * 16 + (lane & 15);          // 0..2047
        int g = col >> 9, hc = col & 511;
        const float* bg = (g == 0) ? bi : (g == 1) ? bf_ : (g == 2) ? bc : bo;
        float bv = bg[hc];
        #pragma unroll
        for (int rf = 0; rf < 2; ++rf)
            #pragma unroll
            for (int r = 0; r < 4; ++r) {
                int row = m0 + w * 32 + rf * 16 + (lane >> 4) * 4 + r;
                xg[(size_t)row * NGATE + col] = acc[rf][cf][r] + bv;
            }
    }
}

// ---------------------------------------------------------------------------
// FUSED persistent kernel, 256 blocks x 512 threads (cooperative):
//  blocks 0..31   : R8 batch-split double-pipeline LSTM scan + READY FLAGS.
//  blocks 32..255 : out_proj GEMM drafting behind the scan. ni-OWNERSHIP:
//    each block owns a fixed 80-col B panel and iterates mi (flag-gated,
//    ascending) -> B working set is a stable 80KB, L1/L2-resident across
//    all mi rounds (B fabric traffic ~10MB instead of ~640MB).
// ---------------------------------------------------------------------------
__global__ __launch_bounds__(512) void lstm_fused(
    const float* __restrict__ xg,
    const unsigned short* __restrict__ WhT,   // [4][512][512] bf16
    unsigned short* hsbf,                     // [128][64][512] bf16 (poisoned)
    float* __restrict__ hfin, float* __restrict__ cfin,
    const unsigned short* __restrict__ Btbf,  // [10000][512] bf16
    const float* __restrict__ bias,           // [10000]
    float* __restrict__ Cout,                 // [8192][10000] f32
    unsigned* flags)                          // [128 t][2 G][32 bx] (pre-zeroed)
{
    __shared__ __align__(16) unsigned char smem[41472];
    const int tid = threadIdx.x;

    if (blockIdx.x < NBLK) {
        // =================== SCAN ROLE (R8 + flags) ========================
        unsigned char* hstage = smem;                               // 32KB
        auto P_lds = reinterpret_cast<float (*)[32][17]>(smem + 32768);
        const int bx   = blockIdx.x;
        const int hc0  = bx * 16;
        const int lane = tid & 63, w = tid >> 6;
        const int wm   = w >> 2, wg = w & 3;

        bf16x8 breg[16];
        {
            const unsigned short* base =
                WhT + ((size_t)wg * HIDDEN + hc0 + (lane & 15)) * HIDDEN + (lane >> 4) * 8;
            #pragma unroll
            for (int ks = 0; ks < 16; ++ks)
                breg[ks] = *reinterpret_cast<const bf16x8*>(base + ks * 32);
        }

        const int ub  = tid >> 3;          // 0..31 (tid<256)
        const int uhp = tid & 7;
        const int uhc = hc0 + uhp * 2;
        float cA0 = 0.f, cA1 = 0.f, cB0 = 0.f, cB1 = 0.f;
        f32x2 xvA[4], xvB[4];
        if (tid < 256) {
            const float* xrA = xg + (size_t)(0 * 32 + ub) * NGATE + uhc;
            const float* xrB = xg + (size_t)(1 * 32 + ub) * NGATE + uhc;
            #pragma unroll
            for (int g = 0; g < 4; ++g) {
                xvA[g] = *reinterpret_cast<const f32x2*>(xrA + g * HIDDEN);
                xvB[g] = *reinterpret_cast<const f32x2*>(xrB + g * HIDDEN);
            }
        }
        unsigned* hs32 = reinterpret_cast<unsigned*>(hsbf);

#define CHK(R) { mx = (mx > (unsigned)R[0]) ? mx : (unsigned)R[0]; \
                 mx = (mx > (unsigned)R[1]) ? mx : (unsigned)R[1]; \
                 mx = (mx > (unsigned)R[2]) ? mx : (unsigned)R[2]; \
                 mx = (mx > (unsigned)R[3]) ? mx : (unsigned)R[3]; }
#define STLDS(R, I) { int s16 = (I) * 512 + tid; int row = s16 >> 6, sl = s16 & 63; \
        *reinterpret_cast<i32x4*>(hstage + row * 1024 + ((sl ^ (row & 7)) << 4)) = R; }

#define GROUP_UPDATE(G, XV, C0, C1, TT)                                         \
    if (tid < 256) {                                                            \
        int hp2 = uhp * 2;                                                      \
        float h0, h1;                                                           \
        cell2(P_lds[0][ub][hp2] + XV[0][0], P_lds[0][ub][hp2+1] + XV[0][1],     \
              P_lds[1][ub][hp2] + XV[1][0], P_lds[1][ub][hp2+1] + XV[1][1],     \
              P_lds[2][ub][hp2] + XV[2][0], P_lds[2][ub][hp2+1] + XV[2][1],     \
              P_lds[3][ub][hp2] + XV[3][0], P_lds[3][ub][hp2+1] + XV[3][1],     \
              C0, C1, h0, h1);                                                  \
        unsigned hp = ((unsigned)f32_to_bf16(h1) << 16) | (unsigned)f32_to_bf16(h0); \
        st4ic(hs32 + (size_t)(TT) * 16384 + ((G) * 32 + ub) * 256 + (uhc >> 1), hp); \
        if ((TT) == T_STEPS - 1) {                                              \
            f32x2 hv = { h0, h1 };                                              \
            *reinterpret_cast<f32x2*>(hfin + (size_t)((G) * 32 + ub) * HIDDEN + uhc) = hv; \
            f32x2 cv = { C0, C1 };                                              \
            *reinterpret_cast<f32x2*>(cfin + (size_t)((G) * 32 + ub) * HIDDEN + uhc) = cv; \
        } else {                                                                \
            const float* xr = xg + (size_t)(((TT) + 1) * BATCH + (G) * 32 + ub) * NGATE + uhc; \
            _Pragma("unroll")                                                   \
            for (int g = 0; g < 4; ++g)                                         \
                XV[g] = *reinterpret_cast<const f32x2*>(xr + g * HIDDEN);       \
        }                                                                       \
    }

#define GROUP_PHASE(G, XV, C0, C1, TT)                                          \
    {                                                                           \
        f32x4 acc = {0.f, 0.f, 0.f, 0.f};                                       \
        {                                                                       \
            const char* hb = (const char*)hsbf + (size_t)((TT) - 1) * 65536 + (G) * 32768; \
            i32x4 q0, q1, q2, q3;                                               \
            for (int rnd = 0; rnd < (1 << 16); ++rnd) {                         \
                q0 = ld16ic(hb + (size_t)(0 * 512 + tid) * 16);                 \
                q1 = ld16ic(hb + (size_t)(1 * 512 + tid) * 16);                 \
                q2 = ld16ic(hb + (size_t)(2 * 512 + tid) * 16);                 \
                q3 = ld16ic(hb + (size_t)(3 * 512 + tid) * 16);                 \
                asm volatile("s_waitcnt vmcnt(0)"                               \
                    : "+v"(q0), "+v"(q1), "+v"(q2), "+v"(q3));                  \
                unsigned mx = 0u;                                               \
                CHK(q0) CHK(q1) CHK(q2) CHK(q3)                                 \
                if (mx != 0xFFFFFFFFu) break;                                   \
                __builtin_amdgcn_s_sleep(1);                                    \
            }                                                                   \
            __builtin_amdgcn_sched_barrier(0);                                  \
            STLDS(q0, 0) STLDS(q1, 1) STLDS(q2, 2) STLDS(q3, 3)                 \
        }                                                                       \
        __syncthreads();   /* implied vmcnt(0): prev slot's publishes ACKed */  \
        if (tid == 0) {                                                         \
            int s_ = 2 * (TT) + (G);                                            \
            int ps = s_ - 1;                                                    \
            st4ic(flags + ((size_t)(ps >> 1) * 64 + (ps & 1) * 32 + bx), 1u);   \
            if (s_ == 2) st4ic(flags + bx, 1u);   /* slot 0 = (A,0) */          \
        }                                                                       \
        {                                                                       \
            const int rr = wm * 16 + (lane & 15);                               \
            _Pragma("unroll")                                                   \
            for (int ks = 0; ks < 16; ++ks) {                                   \
                int sl = ks * 4 + (lane >> 4);                                  \
                bf16x8 a = *reinterpret_cast<const bf16x8*>(                    \
                    hstage + rr * 1024 + ((sl ^ (rr & 7)) << 4));               \
                acc = __builtin_amdgcn_mfma_f32_16x16x32_bf16(a, breg[ks], acc, 0, 0, 0); \
            }                                                                   \
        }                                                                       \
        {                                                                       \
            int colr = lane & 15, rowb = (lane >> 4) * 4;                       \
            _Pragma("unroll")                                                   \
            for (int r = 0; r < 4; ++r)                                         \
                P_lds[wg][wm * 16 + rowb + r][colr] = acc[r];                   \
        }                                                                       \
        __syncthreads();                                                        \
        GROUP_UPDATE(G, XV, C0, C1, TT)                                         \
    }

        // t = 0: registers only
        if (tid < 256) {
            float h0, h1;
            cell2(xvA[0][0], xvA[0][1], xvA[1][0], xvA[1][1],
                  xvA[2][0], xvA[2][1], xvA[3][0], xvA[3][1], cA0, cA1, h0, h1);
            unsigned hp = ((unsigned)f32_to_bf16(h1) << 16) | (unsigned)f32_to_bf16(h0);
            st4ic(hs32 + (size_t)(0 * 32 + ub) * 256 + (uhc >> 1), hp);
            const float* xr = xg + (size_t)(1 * BATCH + 0 * 32 + ub) * NGATE + uhc;
            #pragma unroll
            for (int g = 0; g < 4; ++g)
                xvA[g] = *reinterpret_cast<const f32x2*>(xr + g * HIDDEN);

            cell2(xvB[0][0], xvB[0][1], xvB[1][0], xvB[1][1],
                  xvB[2][0], xvB[2][1], xvB[3][0], xvB[3][1], cB0, cB1, h0, h1);
            hp = ((unsigned)f32_to_bf16(h1) << 16) | (unsigned)f32_to_bf16(h0);
            st4ic(hs32 + (size_t)(1 * 32 + ub) * 256 + (uhc >> 1), hp);
            xr = xg + (size_t)(1 * BATCH + 1 * 32 + ub) * NGATE + uhc;
            #pragma unroll
            for (int g = 0; g < 4; ++g)
                xvB[g] = *reinterpret_cast<const f32x2*>(xr + g * HIDDEN);
        }

        for (int t = 1; t < T_STEPS; ++t) {
            GROUP_PHASE(0, xvA, cA0, cA1, t)
            GROUP_PHASE(1, xvB, cB0, cB1, t)
        }
#undef GROUP_PHASE
#undef GROUP_UPDATE
#undef STLDS
#undef CHK
        // final slot (B,127): drain, then fire its flag
        __syncthreads();
        if (tid == 0)
            st4ic(flags + ((size_t)127 * 64 + 32 + bx), 1u);
    } else {
        // =================== DRAFTING GEMM ROLE (ni ownership) =============
        char* sA = (char*)smem;            // 128 rows x 128B = 16KB
        char* sB = (char*)smem + 16384;    // 80 rows x 128B  = 10KB
        const int gbid = blockIdx.x - NBLK;     // 0..223
        const int w = tid >> 6, lane = tid & 63;
        const unsigned short* __restrict__ Abf = hsbf;   // read-only here

        int ni, mi_lo, mi_hi;
        if (gbid < 99)       { ni = gbid;       mi_lo = 0;  mi_hi = 32; }
        else if (gbid < 125) { ni = gbid;       mi_lo = 0;  mi_hi = 64; }
        else                 { ni = gbid - 125; mi_lo = 32; mi_hi = 64; }
        const int n0 = ni * 80;

        for (int mi = mi_lo; mi < mi_hi; ++mi) {
            int m0 = mi * 128;
            // ---- flag gate: 128 dwords (t = 2mi, 2mi+1; both groups, 32 blks)
            {
                const unsigned* fl = flags + (size_t)2 * mi * 64;
                for (int rnd = 0; rnd < (1 << 20); ++rnd) {
                    unsigned v = 1u;
                    if (tid < 128) v = ld4ic(fl + tid);
                    asm volatile("s_waitcnt vmcnt(0)" : "+v"(v));
                    int bad = (tid < 128) && (v == 0u);
                    if (__syncthreads_count(bad) == 0) break;
                    __builtin_amdgcn_s_sleep(16);
                }
                asm volatile("" ::: "memory");   // keep A loads below the gate
            }
            f32x4 acc[5] = {};
            for (int kc = 0; kc < 8; ++kc) {
                int k0 = kc * 64;
                #pragma unroll
                for (int i = 0; i < 2; ++i) {          // A: 1024 slots, cached
                    int s = tid + i * 512;
                    int row = s >> 3, slot = s & 7;
                    i32x4 v = *reinterpret_cast<const i32x4*>(
                        Abf + (size_t)(m0 + row) * HIDDEN + k0 + slot * 8);
                    *reinterpret_cast<i32x4*>(sA + row * 128 + ((slot ^ (row & 7)) * 16)) = v;
                }
                {                                      // B: 640 slots, L1/L2-hot
                    int s = tid, br = s >> 3, bs = s & 7;
                    i32x4 v = *reinterpret_cast<const i32x4*>(
                        Btbf + (size_t)(n0 + br) * HIDDEN + k0 + bs * 8);
                    *reinterpret_cast<i32x4*>(sB + br * 128 + ((bs ^ (br & 7)) * 16)) = v;
                    if (tid < 128) {
                        s = 512 + tid; br = s >> 3; bs = s & 7;
                        v = *reinterpret_cast<const i32x4*>(
                            Btbf + (size_t)(n0 + br) * HIDDEN + k0 + bs * 8);
                        *reinterpret_cast<i32x4*>(sB + br * 128 + ((bs ^ (br & 7)) * 16)) = v;
                    }
                }
                __syncthreads();
                #pragma unroll
                for (int k2 = 0; k2 < 2; ++k2) {
                    int arow = w * 16 + (lane & 15);
                    int aoff = (k2 * 64 + (lane >> 4) * 16) ^ ((arow & 7) << 4);
                    bf16x8 a = *reinterpret_cast<const bf16x8*>(sA + arow * 128 + aoff);
                    #pragma unroll
                    for (int cf = 0; cf < 5; ++cf) {
                        int brow = cf * 16 + (lane & 15);
                        int boff = (k2 * 64 + (lane >> 4) * 16) ^ ((brow & 7) << 4);
                        bf16x8 b = *reinterpret_cast<const bf16x8*>(sB + brow * 128 + boff);
                        acc[cf] = __builtin_amdgcn_mfma_f32_16x16x32_bf16(a, b, acc[cf], 0, 0, 0);
                    }
                }
                __syncthreads();
            }
            #pragma unroll
            for (int cf = 0; cf < 5; ++cf) {
                int col = n0 + cf * 16 + (lane & 15);
                float bv = bias[col];
                #pragma unroll
                for (int r = 0; r < 4; ++r) {
                    int row = m0 + w * 16 + (lane >> 4) * 4 + r;
                    Cout[(size_t)row * VOCAB + col] = acc[cf][r] + bv;
                }
            }
        }
    }
}

// ---------------------------------------------------------------------------
__global__ void finalize_hc(const float* __restrict__ hfin, const float* __restrict__ cfin,
                            float* __restrict__ out) {
    int i = blockIdx.x * 256 + threadIdx.x;       // 0..65535
    size_t base = (size_t)M_ROWS * VOCAB;
    if (i < BATCH * HIDDEN)
        out[base + i] = hfin[i];
    else
        out[base + i] = cfin[i - BATCH * HIDDEN];
}

extern "C" void kernel_launch(void* const* d_in, const int* in_sizes, int n_in,
                              void* d_out, int out_size, void* d_ws, size_t ws_size,
                              hipStream_t stream) {
    (void)in_sizes; (void)n_in; (void)out_size; (void)ws_size;
    const int*   input_ = (const int*)  d_in[0];
    const float* Emb    = (const float*)d_in[1];
    const float* Wxi    = (const float*)d_in[2];
    const float* Whi    = (const float*)d_in[3];
    const float* bi     = (const float*)d_in[4];
    const float* Wxf    = (const float*)d_in[5];
    const float* Whf    = (const float*)d_in[6];
    const float* bf_    = (const float*)d_in[7];
    const float* Wxc    = (const float*)d_in[8];
    const float* Whc    = (const float*)d_in[9];
    const float* bc     = (const float*)d_in[10];
    const float* Wxo    = (const float*)d_in[11];
    const float* Who    = (const float*)d_in[12];
    const float* bo     = (const float*)d_in[13];
    const float* W      = (const float*)d_in[14];
    const float* b      = (const float*)d_in[15];
    float* out = (float*)d_out;

    char* ws = (char*)d_ws;
    float*          xg   = (float*)         (ws);                 // 67,108,864
    unsigned short* hsbf = (unsigned short*)(ws +  67108864);     //  8,388,608
    unsigned short* Wtbf = (unsigned short*)(ws +  75497472);     // 10,240,000
    unsigned short* WhT  = (unsigned short*)(ws +  85737472);     //  2,097,152
    unsigned short* Embb = (unsigned short*)(ws +  87834624);     //  5,120,000
    unsigned short* WxT  = (unsigned short*)(ws +  92954624);     //  1,048,576
    float*          hfin = (float*)         (ws +  94003200);     //    131,072
    float*          cbuf = (float*)         (ws +  94134272);     //    131,072
    unsigned*       flags= (unsigned*)      (ws +  94265344);     //     32,768

    poison_hsbf<<<2057, 256, 0, stream>>>((unsigned*)hsbf, flags);
    wt_convert<<<dim3(313, 16), dim3(32, 32), 0, stream>>>(W, Wtbf);
    wh_convert<<<dim3(16, 16, 4), dim3(32, 32), 0, stream>>>(Whi, Whf, Whc, Who, WhT);
    emb_convert<<<2500, 256, 0, stream>>>(Emb, Embb);
    wx_convert<<<dim3(16, 8, 4), dim3(32, 32), 0, stream>>>(Wxi, Wxf, Wxc, Wxo, WxT);
    xproj_mfma<<<dim3(32, 64), 256, 0, stream>>>(input_, Embb, WxT, bi, bf_, bc, bo, xg);

    {
        const float* xg_c = xg;
        const unsigned short* WhT_c = WhT;
        unsigned short* hsbf_p = hsbf;
        float* hfin_p = hfin; float* cbuf_p = cbuf;
        const unsigned short* Wtbf_c = Wtbf;
        const float* b_c = b;
        float* out_p = out;
        unsigned* flags_p = flags;
        void* args[] = { (void*)&xg_c, (void*)&WhT_c, (void*)&hsbf_p,
                         (void*)&hfin_p, (void*)&cbuf_p,
                         (void*)&Wtbf_c, (void*)&b_c, (void*)&out_p, (void*)&flags_p };
        hipLaunchCooperativeKernel((void*)lstm_fused, dim3(NLAUNCH), dim3(512), args, 0, stream);
    }

    finalize_hc<<<256, 256, 0, stream>>>(hfin, cbuf, out);
}

// Round 15
// 600.822 us; speedup vs baseline: 1.0794x; 1.0244x over previous
//
#include <hip/hip_runtime.h>
#include <stdint.h>

#define T_STEPS 128
#define BATCH   64
#define EMBED   256
#define HIDDEN  512
#define VOCAB   10000
#define M_ROWS  (T_STEPS*BATCH)   // 8192
#define NGATE   (4*HIDDEN)        // 2048
#define NBLK    32                // lstm worker blocks
#define NLAUNCH 256               // total cooperative blocks
#define NGEMM   (NLAUNCH-NBLK)    // 224 drafting GEMM blocks
#define NTILE_N 125               // 10000/80
#define NTILE_M 64                // 8192/128

typedef __attribute__((ext_vector_type(2))) float  f32x2;
typedef __attribute__((ext_vector_type(4))) float  f32x4;
typedef __attribute__((ext_vector_type(4))) int    i32x4;
typedef __attribute__((ext_vector_type(8))) __bf16 bf16x8;

static __device__ __forceinline__ unsigned short f32_to_bf16(float f) {
    union { float f; uint32_t u; } v; v.f = f;
    uint32_t u = v.u;
    return (unsigned short)((u + 0x7FFFu + ((u >> 16) & 1u)) >> 16);  // RNE
}
static __device__ __forceinline__ float sigf(float x) {
    return 1.f / (1.f + __expf(-x));
}
static __device__ __forceinline__ float tanhfast(float x) {
    float e = __expf(2.f * fminf(fmaxf(x, -15.f), 15.f));
    return (e - 1.f) / (e + 1.f);
}
static __device__ __forceinline__ void cell2(
    float pi0, float pi1, float pf0, float pf1, float pg0, float pg1,
    float po0, float po1, float& c0, float& c1, float& h0, float& h1) {
    float i0 = sigf(pi0), i1 = sigf(pi1);
    float f0 = sigf(pf0), f1 = sigf(pf1);
    float g0 = tanhfast(pg0), g1 = tanhfast(pg1);
    float o0 = sigf(po0), o1 = sigf(po1);
    c0 = f0 * c0 + i0 * g0;
    c1 = f1 * c1 + i1 * g1;
    h0 = o0 * tanhfast(c0);
    h1 = o1 * tanhfast(c1);
}

// IC-coherent (bypass L1+L2) primitives — the verified cross-XCD path.
static __device__ __forceinline__ i32x4 ld16ic(const void* p) {
    i32x4 r; asm volatile("global_load_dwordx4 %0, %1, off sc0 sc1" : "=v"(r) : "v"(p)); return r;
}
static __device__ __forceinline__ unsigned ld4ic(const void* p) {
    unsigned r; asm volatile("global_load_dword %0, %1, off sc0 sc1" : "=v"(r) : "v"(p)); return r;
}
static __device__ __forceinline__ void st4ic(void* p, unsigned v) {
    asm volatile("global_store_dword %0, %1, off sc0 sc1" :: "v"(p), "v"(v) : "memory");
}

// ---------------------------------------------------------------------------
// prep0: Emb f32->bf16 (grid-stride job 1) + poison hsbf sentinel + zero
// flags (jobs 2,3). One launch instead of two.
// ---------------------------------------------------------------------------
__global__ void prep0(const float* __restrict__ E, unsigned short* __restrict__ Eb,
                      unsigned* __restrict__ hs, unsigned* __restrict__ fl) {
    size_t t = (size_t)blockIdx.x * 256 + threadIdx.x;   // 640,000 threads
    size_t i = t * 4;
    if (i < (size_t)VOCAB * EMBED) {
        f32x4 v = *reinterpret_cast<const f32x4*>(E + i);
        unsigned short o[4];
        #pragma unroll
        for (int j = 0; j < 4; ++j) o[j] = f32_to_bf16(v[j]);
        *reinterpret_cast<unsigned long long*>(Eb + i) =
            ((unsigned long long)o[3] << 48) | ((unsigned long long)o[2] << 32) |
            ((unsigned long long)o[1] << 16) | (unsigned long long)o[0];
    }
    if (t < 524288) {
        i32x4 v = { -1, -1, -1, -1 };
        asm volatile("global_store_dwordx4 %0, %1, off sc0 sc1"
                     :: "v"((char*)hs + t * 16), "v"(v) : "memory");
    }
    if (t < 2048) {
        i32x4 z = { 0, 0, 0, 0 };
        asm volatile("global_store_dwordx4 %0, %1, off sc0 sc1"
                     :: "v"((char*)fl + t * 16), "v"(z) : "memory");
    }
}

// ---------------------------------------------------------------------------
__global__ void wt_convert(const float* __restrict__ W, unsigned short* __restrict__ Wt) {
    __shared__ float tile[32][33];
    int n0 = blockIdx.x * 32;
    int k0 = blockIdx.y * 32;
    int tx = threadIdx.x, ty = threadIdx.y;
    int n = n0 + tx;
    if (n < VOCAB) tile[ty][tx] = W[(size_t)(k0 + ty) * VOCAB + n];
    __syncthreads();
    int nn = n0 + ty;
    if (nn < VOCAB) Wt[(size_t)nn * HIDDEN + k0 + tx] = f32_to_bf16(tile[tx][ty]);
}

// ---------------------------------------------------------------------------
__global__ void wh_convert(const float* __restrict__ Whi, const float* __restrict__ Whf,
                           const float* __restrict__ Whc, const float* __restrict__ Who,
                           unsigned short* __restrict__ WhT) {
    __shared__ float tile[32][33];
    int g = blockIdx.z;
    const float* Wg = (g == 0) ? Whi : (g == 1) ? Whf : (g == 2) ? Whc : Who;
    int n0 = blockIdx.x * 32, k0 = blockIdx.y * 32;
    int tx = threadIdx.x, ty = threadIdx.y;
    tile[ty][tx] = Wg[(size_t)(k0 + ty) * HIDDEN + n0 + tx];
    __syncthreads();
    WhT[((size_t)g * HIDDEN + n0 + ty) * HIDDEN + k0 + tx] = f32_to_bf16(tile[tx][ty]);
}

// ---------------------------------------------------------------------------
// Wx_g [256 k][512 n] f32 -> WxT [2048 n][256 k] bf16
// ---------------------------------------------------------------------------
__global__ void wx_convert(const float* __restrict__ Wxi, const float* __restrict__ Wxf,
                           const float* __restrict__ Wxc, const float* __restrict__ Wxo,
                           unsigned short* __restrict__ WxT) {
    __shared__ float tile[32][33];
    int g = blockIdx.z;
    const float* Wg = (g == 0) ? Wxi : (g == 1) ? Wxf : (g == 2) ? Wxc : Wxo;
    int n0 = blockIdx.x * 32, k0 = blockIdx.y * 32;   // n<512, k<256
    int tx = threadIdx.x, ty = threadIdx.y;
    tile[ty][tx] = Wg[(size_t)(k0 + ty) * HIDDEN + n0 + tx];
    __syncthreads();
    WxT[((size_t)g * HIDDEN + n0 + ty) * EMBED + k0 + tx] = f32_to_bf16(tile[tx][ty]);
}

// ---------------------------------------------------------------------------
// xg[m][c] = embeds_bf16[m,:] @ WxT[c,:]^T + b   (bf16 MFMA, f32 out)
// ---------------------------------------------------------------------------
__global__ __launch_bounds__(256) void xproj_mfma(
    const int* __restrict__ idx, const unsigned short* __restrict__ Eb,
    const unsigned short* __restrict__ WxT,
    const float* __restrict__ bi,  const float* __restrict__ bf_,
    const float* __restrict__ bc,  const float* __restrict__ bo,
    float* __restrict__ xg)
{
    __shared__ __align__(16) char sA[128 * 128];  // 128 rows x 64 bf16
    __shared__ __align__(16) char sB[64 * 128];   // 64 rows x 64 bf16
    int n0 = blockIdx.x * 64;
    int m0 = blockIdx.y * 128;
    int tid = threadIdx.x;
    int w = tid >> 6, lane = tid & 63;
    f32x4 acc[2][4] = {};

    int arow[4], aer[4];
    #pragma unroll
    for (int i = 0; i < 4; ++i) {
        int s = tid + i * 256;
        arow[i] = s >> 3;
        aer[i]  = idx[m0 + arow[i]];
    }

    for (int kc = 0; kc < 4; ++kc) {
        int k0 = kc * 64;
        #pragma unroll
        for (int i = 0; i < 4; ++i) {                  // A: 1024 16B slots
            int s = tid + i * 256;
            int row = arow[i], slot = s & 7;
            i32x4 v = *reinterpret_cast<const i32x4*>(Eb + (size_t)aer[i] * EMBED + k0 + slot * 8);
            *reinterpret_cast<i32x4*>(sA + row * 128 + ((slot ^ (row & 7)) * 16)) = v;
        }
        #pragma unroll
        for (int i = 0; i < 2; ++i) {                  // B: 512 slots
            int s = tid + i * 256;
            int row = s >> 3, slot = s & 7;
            i32x4 v = *reinterpret_cast<const i32x4*>(WxT + (size_t)(n0 + row) * EMBED + k0 + slot * 8);
            *reinterpret_cast<i32x4*>(sB + row * 128 + ((slot ^ (row & 7)) * 16)) = v;
        }
        __syncthreads();
        #pragma unroll
        for (int k2 = 0; k2 < 2; ++k2) {
            bf16x8 a[2], b[4];
            #pragma unroll
            for (int rf = 0; rf < 2; ++rf) {
                int row = w * 32 + rf * 16 + (lane & 15);
                int off = (k2 * 64 + (lane >> 4) * 16) ^ ((row & 7) << 4);
                a[rf] = *reinterpret_cast<const bf16x8*>(sA + row * 128 + off);
            }
            #pragma unroll
            for (int cf = 0; cf < 4; ++cf) {
                int row = cf * 16 + (lane & 15);
                int off = (k2 * 64 + (lane >> 4) * 16) ^ ((row & 7) << 4);
                b[cf] = *reinterpret_cast<const bf16x8*>(sB + row * 128 + off);
            }
            #pragma unroll
            for (int rf = 0; rf < 2; ++rf)
                #pragma unroll
                for (int cf = 0; cf < 4; ++cf)
                    acc[rf][cf] = __builtin_amdgcn_mfma_f32_16x16x32_bf16(a[rf], b[cf], acc[rf][cf], 0, 0, 0);
        }
        __syncthreads();
    }
    #pragma unroll
    for (int cf = 0; cf < 4; ++cf) {
        int col = n0 + cf * 16 + (lane & 15);          // 0..2047
        int g = col >> 9, hc = col & 511;
        const float* bg = (g == 0) ? bi : (g == 1) ? bf_ : (g == 2) ? bc : bo;
        float bv = bg[hc];
        #pragma unroll
        for (int rf = 0; rf < 2; ++rf)
            #pragma unroll
            for (int r = 0; r < 4; ++r) {
                int row = m0 + w * 32 + rf * 16 + (lane >> 4) * 4 + r;
                xg[(size_t)row * NGATE + col] = acc[rf][cf][r] + bv;
            }
    }
}

// ---------------------------------------------------------------------------
// FUSED persistent kernel, 256 blocks x 512 threads (cooperative):
//  blocks 0..31   : R8 scan + ready flags (finals written DIRECTLY to out).
//  blocks 32..255 : out_proj GEMM, ni-ownership, flag-gated, REGISTER
//                   DOUBLE-BUFFERED k-loop (issue kc+1 loads under kc MFMA).
// ---------------------------------------------------------------------------
__global__ __launch_bounds__(512) void lstm_fused(
    const float* __restrict__ xg,
    const unsigned short* __restrict__ WhT,   // [4][512][512] bf16
    unsigned short* hsbf,                     // [128][64][512] bf16 (poisoned)
    float* __restrict__ outp,                 // out + 8192*10000 (h_t, c_t)
    const unsigned short* __restrict__ Btbf,  // [10000][512] bf16
    const float* __restrict__ bias,           // [10000]
    float* __restrict__ Cout,                 // [8192][10000] f32
    unsigned* flags)                          // [128 t][2 G][32 bx] (pre-zeroed)
{
    __shared__ __align__(16) unsigned char smem[41472];
    const int tid = threadIdx.x;

    if (blockIdx.x < NBLK) {
        // =================== SCAN ROLE (R8 + flags) ========================
        unsigned char* hstage = smem;                               // 32KB
        auto P_lds = reinterpret_cast<float (*)[32][17]>(smem + 32768);
        const int bx   = blockIdx.x;
        const int hc0  = bx * 16;
        const int lane = tid & 63, w = tid >> 6;
        const int wm   = w >> 2, wg = w & 3;

        bf16x8 breg[16];
        {
            const unsigned short* base =
                WhT + ((size_t)wg * HIDDEN + hc0 + (lane & 15)) * HIDDEN + (lane >> 4) * 8;
            #pragma unroll
            for (int ks = 0; ks < 16; ++ks)
                breg[ks] = *reinterpret_cast<const bf16x8*>(base + ks * 32);
        }

        const int ub  = tid >> 3;          // 0..31 (tid<256)
        const int uhp = tid & 7;
        const int uhc = hc0 + uhp * 2;
        float cA0 = 0.f, cA1 = 0.f, cB0 = 0.f, cB1 = 0.f;
        f32x2 xvA[4], xvB[4];
        if (tid < 256) {
            const float* xrA = xg + (size_t)(0 * 32 + ub) * NGATE + uhc;
            const float* xrB = xg + (size_t)(1 * 32 + ub) * NGATE + uhc;
            #pragma unroll
            for (int g = 0; g < 4; ++g) {
                xvA[g] = *reinterpret_cast<const f32x2*>(xrA + g * HIDDEN);
                xvB[g] = *reinterpret_cast<const f32x2*>(xrB + g * HIDDEN);
            }
        }
        unsigned* hs32 = reinterpret_cast<unsigned*>(hsbf);

#define CHK(R) { mx = (mx > (unsigned)R[0]) ? mx : (unsigned)R[0]; \
                 mx = (mx > (unsigned)R[1]) ? mx : (unsigned)R[1]; \
                 mx = (mx > (unsigned)R[2]) ? mx : (unsigned)R[2]; \
                 mx = (mx > (unsigned)R[3]) ? mx : (unsigned)R[3]; }
#define STLDS(R, I) { int s16 = (I) * 512 + tid; int row = s16 >> 6, sl = s16 & 63; \
        *reinterpret_cast<i32x4*>(hstage + row * 1024 + ((sl ^ (row & 7)) << 4)) = R; }

#define GROUP_UPDATE(G, XV, C0, C1, TT)                                         \
    if (tid < 256) {                                                            \
        int hp2 = uhp * 2;                                                      \
        float h0, h1;                                                           \
        cell2(P_lds[0][ub][hp2] + XV[0][0], P_lds[0][ub][hp2+1] + XV[0][1],     \
              P_lds[1][ub][hp2] + XV[1][0], P_lds[1][ub][hp2+1] + XV[1][1],     \
              P_lds[2][ub][hp2] + XV[2][0], P_lds[2][ub][hp2+1] + XV[2][1],     \
              P_lds[3][ub][hp2] + XV[3][0], P_lds[3][ub][hp2+1] + XV[3][1],     \
              C0, C1, h0, h1);                                                  \
        unsigned hp = ((unsigned)f32_to_bf16(h1) << 16) | (unsigned)f32_to_bf16(h0); \
        st4ic(hs32 + (size_t)(TT) * 16384 + ((G) * 32 + ub) * 256 + (uhc >> 1), hp); \
        if ((TT) == T_STEPS - 1) {                                              \
            f32x2 hv = { h0, h1 };                                              \
            *reinterpret_cast<f32x2*>(outp + (size_t)((G) * 32 + ub) * HIDDEN + uhc) = hv; \
            f32x2 cv = { C0, C1 };                                              \
            *reinterpret_cast<f32x2*>(outp + 32768 + (size_t)((G) * 32 + ub) * HIDDEN + uhc) = cv; \
        } else {                                                                \
            const float* xr = xg + (size_t)(((TT) + 1) * BATCH + (G) * 32 + ub) * NGATE + uhc; \
            _Pragma("unroll")                                                   \
            for (int g = 0; g < 4; ++g)                                         \
                XV[g] = *reinterpret_cast<const f32x2*>(xr + g * HIDDEN);       \
        }                                                                       \
    }

#define GROUP_PHASE(G, XV, C0, C1, TT)                                          \
    {                                                                           \
        f32x4 acc = {0.f, 0.f, 0.f, 0.f};                                       \
        {                                                                       \
            const char* hb = (const char*)hsbf + (size_t)((TT) - 1) * 65536 + (G) * 32768; \
            i32x4 q0, q1, q2, q3;                                               \
            for (int rnd = 0; rnd < (1 << 16); ++rnd) {                         \
                q0 = ld16ic(hb + (size_t)(0 * 512 + tid) * 16);                 \
                q1 = ld16ic(hb + (size_t)(1 * 512 + tid) * 16);                 \
                q2 = ld16ic(hb + (size_t)(2 * 512 + tid) * 16);                 \
                q3 = ld16ic(hb + (size_t)(3 * 512 + tid) * 16);                 \
                asm volatile("s_waitcnt vmcnt(0)"                               \
                    : "+v"(q0), "+v"(q1), "+v"(q2), "+v"(q3));                  \
                unsigned mx = 0u;                                               \
                CHK(q0) CHK(q1) CHK(q2) CHK(q3)                                 \
                if (mx != 0xFFFFFFFFu) break;                                   \
                __builtin_amdgcn_s_sleep(1);                                    \
            }                                                                   \
            __builtin_amdgcn_sched_barrier(0);                                  \
            STLDS(q0, 0) STLDS(q1, 1) STLDS(q2, 2) STLDS(q3, 3)                 \
        }                                                                       \
        __syncthreads();   /* implied vmcnt(0): prev slot's publishes ACKed */  \
        if (tid == 0) {                                                         \
            int s_ = 2 * (TT) + (G);                                            \
            int ps = s_ - 1;                                                    \
            st4ic(flags + ((size_t)(ps >> 1) * 64 + (ps & 1) * 32 + bx), 1u);   \
            if (s_ == 2) st4ic(flags + bx, 1u);   /* slot 0 = (A,0) */          \
        }                                                                       \
        {                                                                       \
            const int rr = wm * 16 + (lane & 15);                               \
            _Pragma("unroll")                                                   \
            for (int ks = 0; ks < 16; ++ks) {                                   \
                int sl = ks * 4 + (lane >> 4);                                  \
                bf16x8 a = *reinterpret_cast<const bf16x8*>(                    \
                    hstage + rr * 1024 + ((sl ^ (rr & 7)) << 4));               \
                acc = __builtin_amdgcn_mfma_f32_16x16x32_bf16(a, breg[ks], acc, 0, 0, 0); \
            }                                                                   \
        }                                                                       \
        {                                                                       \
            int colr = lane & 15, rowb = (lane >> 4) * 4;                       \
            _Pragma("unroll")                                                   \
            for (int r = 0; r < 4; ++r)                                         \
                P_lds[wg][wm * 16 + rowb + r][colr] = acc[r];                   \
        }                                                                       \
        __syncthreads();                                                        \
        GROUP_UPDATE(G, XV, C0, C1, TT)                                         \
    }

        // t = 0: registers only
        if (tid < 256) {
            float h0, h1;
            cell2(xvA[0][0], xvA[0][1], xvA[1][0], xvA[1][1],
                  xvA[2][0], xvA[2][1], xvA[3][0], xvA[3][1], cA0, cA1, h0, h1);
            unsigned hp = ((unsigned)f32_to_bf16(h1) << 16) | (unsigned)f32_to_bf16(h0);
            st4ic(hs32 + (size_t)(0 * 32 + ub) * 256 + (uhc >> 1), hp);
            const float* xr = xg + (size_t)(1 * BATCH + 0 * 32 + ub) * NGATE + uhc;
            #pragma unroll
            for (int g = 0; g < 4; ++g)
                xvA[g] = *reinterpret_cast<const f32x2*>(xr + g * HIDDEN);

            cell2(xvB[0][0], xvB[0][1], xvB[1][0], xvB[1][1],
                  xvB[2][0], xvB[2][1], xvB[3][0], xvB[3][1], cB0, cB1, h0, h1);
            hp = ((unsigned)f32_to_bf16(h1) << 16) | (unsigned)f32_to_bf16(h0);
            st4ic(hs32 + (size_t)(1 * 32 + ub) * 256 + (uhc >> 1), hp);
            xr = xg + (size_t)(1 * BATCH + 1 * 32 + ub) * NGATE + uhc;
            #pragma unroll
            for (int g = 0; g < 4; ++g)
                xvB[g] = *reinterpret_cast<const f32x2*>(xr + g * HIDDEN);
        }

        for (int t = 1; t < T_STEPS; ++t) {
            GROUP_PHASE(0, xvA, cA0, cA1, t)
            GROUP_PHASE(1, xvB, cB0, cB1, t)
        }
#undef GROUP_PHASE
#undef GROUP_UPDATE
#undef STLDS
#undef CHK
        // final slot (B,127): drain, then fire its flag
        __syncthreads();
        if (tid == 0)
            st4ic(flags + ((size_t)127 * 64 + 32 + bx), 1u);
    } else {
        // ============ DRAFTING GEMM ROLE (ni ownership + reg dbuf) =========
        char* sA = (char*)smem;            // 128 rows x 128B = 16KB
        char* sB = (char*)smem + 16384;    // 80 rows x 128B  = 10KB
        const int gbid = blockIdx.x - NBLK;     // 0..223
        const int w = tid >> 6, lane = tid & 63;
        const unsigned short* __restrict__ Abf = hsbf;   // read-only here

        int ni, mi_lo, mi_hi;
        if (gbid < 99)       { ni = gbid;       mi_lo = 0;  mi_hi = 32; }
        else if (gbid < 125) { ni = gbid;       mi_lo = 0;  mi_hi = 64; }
        else                 { ni = gbid - 125; mi_lo = 32; mi_hi = 64; }
        const int n0 = ni * 80;

        // per-thread staging geometry (fixed across kc)
        const int ar0 = tid >> 3, ar1 = (tid >> 3) + 64, aslot = tid & 7;  // A rows/slot
        const int br0 = tid >> 3, bs0 = tid & 7;                           // B first
        const int br1 = (512 + tid) >> 3, bs1 = tid & 7;                   // B second (tid<128)

        for (int mi = mi_lo; mi < mi_hi; ++mi) {
            int m0 = mi * 128;
            // ---- flag gate: 128 dwords (t = 2mi, 2mi+1; both groups, 32 blks)
            {
                const unsigned* fl = flags + (size_t)2 * mi * 64;
                for (int rnd = 0; rnd < (1 << 20); ++rnd) {
                    unsigned v = 1u;
                    if (tid < 128) v = ld4ic(fl + tid);
                    asm volatile("s_waitcnt vmcnt(0)" : "+v"(v));
                    int bad = (tid < 128) && (v == 0u);
                    if (__syncthreads_count(bad) == 0) break;
                    __builtin_amdgcn_s_sleep(16);
                }
                asm volatile("" ::: "memory");   // keep A loads below the gate
            }
            f32x4 acc[5] = {};
            i32x4 ra0, ra1, rb0, rb1;
            // prologue: issue kc=0 loads (cached; post-flag => safe)
            {
                ra0 = *reinterpret_cast<const i32x4*>(Abf + (size_t)(m0 + ar0) * HIDDEN + aslot * 8);
                ra1 = *reinterpret_cast<const i32x4*>(Abf + (size_t)(m0 + ar1) * HIDDEN + aslot * 8);
                rb0 = *reinterpret_cast<const i32x4*>(Btbf + (size_t)(n0 + br0) * HIDDEN + bs0 * 8);
                if (tid < 128)
                    rb1 = *reinterpret_cast<const i32x4*>(Btbf + (size_t)(n0 + br1) * HIDDEN + bs1 * 8);
            }
            for (int kc = 0; kc < 8; ++kc) {
                // regs -> LDS (compiler inserts vmcnt waits on first use)
                *reinterpret_cast<i32x4*>(sA + ar0 * 128 + ((aslot ^ (ar0 & 7)) * 16)) = ra0;
                *reinterpret_cast<i32x4*>(sA + ar1 * 128 + ((aslot ^ (ar1 & 7)) * 16)) = ra1;
                *reinterpret_cast<i32x4*>(sB + br0 * 128 + ((bs0 ^ (br0 & 7)) * 16)) = rb0;
                if (tid < 128)
                    *reinterpret_cast<i32x4*>(sB + br1 * 128 + ((bs1 ^ (br1 & 7)) * 16)) = rb1;
                __syncthreads();
                // issue kc+1 loads: fly under the MFMA below + next syncs
                if (kc < 7) {
                    int k1 = (kc + 1) * 64;
                    ra0 = *reinterpret_cast<const i32x4*>(Abf + (size_t)(m0 + ar0) * HIDDEN + k1 + aslot * 8);
                    ra1 = *reinterpret_cast<const i32x4*>(Abf + (size_t)(m0 + ar1) * HIDDEN + k1 + aslot * 8);
                    rb0 = *reinterpret_cast<const i32x4*>(Btbf + (size_t)(n0 + br0) * HIDDEN + k1 + bs0 * 8);
                    if (tid < 128)
                        rb1 = *reinterpret_cast<const i32x4*>(Btbf + (size_t)(n0 + br1) * HIDDEN + k1 + bs1 * 8);
                }
                #pragma unroll
                for (int k2 = 0; k2 < 2; ++k2) {
                    int arow = w * 16 + (lane & 15);
                    int aoff = (k2 * 64 + (lane >> 4) * 16) ^ ((arow & 7) << 4);
                    bf16x8 a = *reinterpret_cast<const bf16x8*>(sA + arow * 128 + aoff);
                    #pragma unroll
                    for (int cf = 0; cf < 5; ++cf) {
                        int brow = cf * 16 + (lane & 15);
                        int boff = (k2 * 64 + (lane >> 4) * 16) ^ ((brow & 7) << 4);
                        bf16x8 b = *reinterpret_cast<const bf16x8*>(sB + brow * 128 + boff);
                        acc[cf] = __builtin_amdgcn_mfma_f32_16x16x32_bf16(a, b, acc[cf], 0, 0, 0);
                    }
                }
                __syncthreads();
            }
            #pragma unroll
            for (int cf = 0; cf < 5; ++cf) {
                int col = n0 + cf * 16 + (lane & 15);
                float bv = bias[col];
                #pragma unroll
                for (int r = 0; r < 4; ++r) {
                    int row = m0 + w * 16 + (lane >> 4) * 4 + r;
                    Cout[(size_t)row * VOCAB + col] = acc[cf][r] + bv;
                }
            }
        }
    }
}

extern "C" void kernel_launch(void* const* d_in, const int* in_sizes, int n_in,
                              void* d_out, int out_size, void* d_ws, size_t ws_size,
                              hipStream_t stream) {
    (void)in_sizes; (void)n_in; (void)out_size; (void)ws_size;
    const int*   input_ = (const int*)  d_in[0];
    const float* Emb    = (const float*)d_in[1];
    const float* Wxi    = (const float*)d_in[2];
    const float* Whi    = (const float*)d_in[3];
    const float* bi     = (const float*)d_in[4];
    const float* Wxf    = (const float*)d_in[5];
    const float* Whf    = (const float*)d_in[6];
    const float* bf_    = (const float*)d_in[7];
    const float* Wxc    = (const float*)d_in[8];
    const float* Whc    = (const float*)d_in[9];
    const float* bc     = (const float*)d_in[10];
    const float* Wxo    = (const float*)d_in[11];
    const float* Who    = (const float*)d_in[12];
    const float* bo     = (const float*)d_in[13];
    const float* W      = (const float*)d_in[14];
    const float* b      = (const float*)d_in[15];
    float* out = (float*)d_out;

    char* ws = (char*)d_ws;
    float*          xg   = (float*)         (ws);                 // 67,108,864
    unsigned short* hsbf = (unsigned short*)(ws +  67108864);     //  8,388,608
    unsigned short* Wtbf = (unsigned short*)(ws +  75497472);     // 10,240,000
    unsigned short* WhT  = (unsigned short*)(ws +  85737472);     //  2,097,152
    unsigned short* Embb = (unsigned short*)(ws +  87834624);     //  5,120,000
    unsigned short* WxT  = (unsigned short*)(ws +  92954624);     //  1,048,576
    unsigned*       flags= (unsigned*)      (ws +  94003200);     //     32,768

    prep0<<<2500, 256, 0, stream>>>(Emb, Embb, (unsigned*)hsbf, flags);
    wt_convert<<<dim3(313, 16), dim3(32, 32), 0, stream>>>(W, Wtbf);
    wh_convert<<<dim3(16, 16, 4), dim3(32, 32), 0, stream>>>(Whi, Whf, Whc, Who, WhT);
    wx_convert<<<dim3(16, 8, 4), dim3(32, 32), 0, stream>>>(Wxi, Wxf, Wxc, Wxo, WxT);
    xproj_mfma<<<dim3(32, 64), 256, 0, stream>>>(input_, Embb, WxT, bi, bf_, bc, bo, xg);

    {
        const float* xg_c = xg;
        const unsigned short* WhT_c = WhT;
        unsigned short* hsbf_p = hsbf;
        float* outp = out + (size_t)M_ROWS * VOCAB;
        const unsigned short* Wtbf_c = Wtbf;
        const float* b_c = b;
        float* out_p = out;
        unsigned* flags_p = flags;
        void* args[] = { (void*)&xg_c, (void*)&WhT_c, (void*)&hsbf_p,
                         (void*)&outp,
                         (void*)&Wtbf_c, (void*)&b_c, (void*)&out_p, (void*)&flags_p };
        hipLaunchCooperativeKernel((void*)lstm_fused, dim3(NLAUNCH), dim3(512), args, 0, stream);
    }
}

// Round 16
// 580.847 us; speedup vs baseline: 1.1165x; 1.0344x over previous
//
#include <hip/hip_runtime.h>
#include <stdint.h>

#define T_STEPS 128
#define BATCH   64
#define EMBED   256
#define HIDDEN  512
#define VOCAB   10000
#define M_ROWS  (T_STEPS*BATCH)   // 8192
#define NGATE   (4*HIDDEN)        // 2048
#define NBLK    32                // lstm worker blocks
#define NLAUNCH 256               // total cooperative blocks
#define NGEMM   (NLAUNCH-NBLK)    // 224 drafting GEMM blocks
#define NTILE_N 125               // 10000/80
#define NTILE_M 64                // 8192/128

typedef __attribute__((ext_vector_type(2))) float  f32x2;
typedef __attribute__((ext_vector_type(4))) float  f32x4;
typedef __attribute__((ext_vector_type(4))) int    i32x4;
typedef __attribute__((ext_vector_type(8))) __bf16 bf16x8;

static __device__ __forceinline__ unsigned short f32_to_bf16(float f) {
    union { float f; uint32_t u; } v; v.f = f;
    uint32_t u = v.u;
    return (unsigned short)((u + 0x7FFFu + ((u >> 16) & 1u)) >> 16);  // RNE
}
static __device__ __forceinline__ float sigf(float x) {
    return 1.f / (1.f + __expf(-x));
}
static __device__ __forceinline__ float tanhfast(float x) {
    float e = __expf(2.f * fminf(fmaxf(x, -15.f), 15.f));
    return (e - 1.f) / (e + 1.f);
}
static __device__ __forceinline__ void cell2(
    float pi0, float pi1, float pf0, float pf1, float pg0, float pg1,
    float po0, float po1, float& c0, float& c1, float& h0, float& h1) {
    float i0 = sigf(pi0), i1 = sigf(pi1);
    float f0 = sigf(pf0), f1 = sigf(pf1);
    float g0 = tanhfast(pg0), g1 = tanhfast(pg1);
    float o0 = sigf(po0), o1 = sigf(po1);
    c0 = f0 * c0 + i0 * g0;
    c1 = f1 * c1 + i1 * g1;
    h0 = o0 * tanhfast(c0);
    h1 = o1 * tanhfast(c1);
}

// IC-coherent (bypass L1+L2) primitives — the verified cross-XCD path.
static __device__ __forceinline__ i32x4 ld16ic(const void* p) {
    i32x4 r; asm volatile("global_load_dwordx4 %0, %1, off sc0 sc1" : "=v"(r) : "v"(p)); return r;
}
static __device__ __forceinline__ unsigned ld4ic(const void* p) {
    unsigned r; asm volatile("global_load_dword %0, %1, off sc0 sc1" : "=v"(r) : "v"(p)); return r;
}
static __device__ __forceinline__ void st4ic(void* p, unsigned v) {
    asm volatile("global_store_dword %0, %1, off sc0 sc1" :: "v"(p), "v"(v) : "memory");
}
// non-temporal scalar store: no MALL allocation for the C stream
static __device__ __forceinline__ void st4nt(void* p, float v) {
    asm volatile("global_store_dword %0, %1, off nt" :: "v"(p), "v"(v) : "memory");
}

// ---------------------------------------------------------------------------
// prep_all (1024 thr): blocks 0..624 = Emb f32->bf16 + poison hsbf + zero
// flags/ctr; blocks 625..1648 = Wh transpose-convert; 1649..2160 = Wx.
// ---------------------------------------------------------------------------
__global__ __launch_bounds__(1024) void prep_all(
    const float* __restrict__ E, unsigned short* __restrict__ Eb,
    unsigned* __restrict__ hs, unsigned* __restrict__ fl,
    const float* __restrict__ Whi, const float* __restrict__ Whf,
    const float* __restrict__ Whc, const float* __restrict__ Who,
    unsigned short* __restrict__ WhT,
    const float* __restrict__ Wxi, const float* __restrict__ Wxf,
    const float* __restrict__ Wxc, const float* __restrict__ Wxo,
    unsigned short* __restrict__ WxT)
{
    __shared__ float tile[32][33];
    const int bid = blockIdx.x, tid = threadIdx.x;
    if (bid < 625) {
        size_t t = (size_t)bid * 1024 + tid;       // 0..639,999
        size_t i = t * 4;
        if (i < (size_t)VOCAB * EMBED) {
            f32x4 v = *reinterpret_cast<const f32x4*>(E + i);
            unsigned short o[4];
            #pragma unroll
            for (int j = 0; j < 4; ++j) o[j] = f32_to_bf16(v[j]);
            *reinterpret_cast<unsigned long long*>(Eb + i) =
                ((unsigned long long)o[3] << 48) | ((unsigned long long)o[2] << 32) |
                ((unsigned long long)o[1] << 16) | (unsigned long long)o[0];
        }
        if (t < 524288) {
            i32x4 v = { -1, -1, -1, -1 };
            asm volatile("global_store_dwordx4 %0, %1, off sc0 sc1"
                         :: "v"((char*)hs + t * 16), "v"(v) : "memory");
        }
        if (t < 2052) {   // 32KB flags + 64B wt-convert counter area
            i32x4 z = { 0, 0, 0, 0 };
            asm volatile("global_store_dwordx4 %0, %1, off sc0 sc1"
                         :: "v"((char*)fl + t * 16), "v"(z) : "memory");
        }
    } else if (bid < 625 + 1024) {
        int e = bid - 625;
        int g = e >> 8, rem = e & 255;
        int n0 = (rem >> 4) * 32, k0 = (rem & 15) * 32;
        const float* Wg = (g == 0) ? Whi : (g == 1) ? Whf : (g == 2) ? Whc : Who;
        int tx = tid & 31, ty = tid >> 5;
        tile[ty][tx] = Wg[(size_t)(k0 + ty) * HIDDEN + n0 + tx];
        __syncthreads();
        WhT[((size_t)g * HIDDEN + n0 + ty) * HIDDEN + k0 + tx] = f32_to_bf16(tile[tx][ty]);
    } else {
        int e = bid - 1649;
        int g = e >> 7, rem = e & 127;
        int n0 = (rem >> 3) * 32, k0 = (rem & 7) * 32;
        const float* Wg = (g == 0) ? Wxi : (g == 1) ? Wxf : (g == 2) ? Wxc : Wxo;
        int tx = tid & 31, ty = tid >> 5;
        tile[ty][tx] = Wg[(size_t)(k0 + ty) * HIDDEN + n0 + tx];
        __syncthreads();
        WxT[((size_t)g * HIDDEN + n0 + ty) * EMBED + k0 + tx] = f32_to_bf16(tile[tx][ty]);
    }
}

// ---------------------------------------------------------------------------
// xg[m][c] = embeds_bf16[m,:] @ WxT[c,:]^T + b   (bf16 MFMA, f32 out)
// ---------------------------------------------------------------------------
__global__ __launch_bounds__(256) void xproj_mfma(
    const int* __restrict__ idx, const unsigned short* __restrict__ Eb,
    const unsigned short* __restrict__ WxT,
    const float* __restrict__ bi,  const float* __restrict__ bf_,
    const float* __restrict__ bc,  const float* __restrict__ bo,
    float* __restrict__ xg)
{
    __shared__ __align__(16) char sA[128 * 128];  // 128 rows x 64 bf16
    __shared__ __align__(16) char sB[64 * 128];   // 64 rows x 64 bf16
    int n0 = blockIdx.x * 64;
    int m0 = blockIdx.y * 128;
    int tid = threadIdx.x;
    int w = tid >> 6, lane = tid & 63;
    f32x4 acc[2][4] = {};

    int arow[4], aer[4];
    #pragma unroll
    for (int i = 0; i < 4; ++i) {
        int s = tid + i * 256;
        arow[i] = s >> 3;
        aer[i]  = idx[m0 + arow[i]];
    }

    for (int kc = 0; kc < 4; ++kc) {
        int k0 = kc * 64;
        #pragma unroll
        for (int i = 0; i < 4; ++i) {                  // A: 1024 16B slots
            int s = tid + i * 256;
            int row = arow[i], slot = s & 7;
            i32x4 v = *reinterpret_cast<const i32x4*>(Eb + (size_t)aer[i] * EMBED + k0 + slot * 8);
            *reinterpret_cast<i32x4*>(sA + row * 128 + ((slot ^ (row & 7)) * 16)) = v;
        }
        #pragma unroll
        for (int i = 0; i < 2; ++i) {                  // B: 512 slots
            int s = tid + i * 256;
            int row = s >> 3, slot = s & 7;
            i32x4 v = *reinterpret_cast<const i32x4*>(WxT + (size_t)(n0 + row) * EMBED + k0 + slot * 8);
            *reinterpret_cast<i32x4*>(sB + row * 128 + ((slot ^ (row & 7)) * 16)) = v;
        }
        __syncthreads();
        #pragma unroll
        for (int k2 = 0; k2 < 2; ++k2) {
            bf16x8 a[2], b[4];
            #pragma unroll
            for (int rf = 0; rf < 2; ++rf) {
                int row = w * 32 + rf * 16 + (lane & 15);
                int off = (k2 * 64 + (lane >> 4) * 16) ^ ((row & 7) << 4);
                a[rf] = *reinterpret_cast<const bf16x8*>(sA + row * 128 + off);
            }
            #pragma unroll
            for (int cf = 0; cf < 4; ++cf) {
                int row = cf * 16 + (lane & 15);
                int off = (k2 * 64 + (lane >> 4) * 16) ^ ((row & 7) << 4);
                b[cf] = *reinterpret_cast<const bf16x8*>(sB + row * 128 + off);
            }
            #pragma unroll
            for (int rf = 0; rf < 2; ++rf)
                #pragma unroll
                for (int cf = 0; cf < 4; ++cf)
                    acc[rf][cf] = __builtin_amdgcn_mfma_f32_16x16x32_bf16(a[rf], b[cf], acc[rf][cf], 0, 0, 0);
        }
        __syncthreads();
    }
    #pragma unroll
    for (int cf = 0; cf < 4; ++cf) {
        int col = n0 + cf * 16 + (lane & 15);          // 0..2047
        int g = col >> 9, hc = col & 511;
        const float* bg = (g == 0) ? bi : (g == 1) ? bf_ : (g == 2) ? bc : bo;
        float bv = bg[hc];
        #pragma unroll
        for (int rf = 0; rf < 2; ++rf)
            #pragma unroll
            for (int r = 0; r < 4; ++r) {
                int row = m0 + w * 32 + rf * 16 + (lane >> 4) * 4 + r;
                xg[(size_t)row * NGATE + col] = acc[rf][cf][r] + bv;
            }
    }
}

// ---------------------------------------------------------------------------
// FUSED persistent kernel, 256 blocks x 512 threads (cooperative):
//  blocks 0..31   : R8 scan + ready flags (finals written DIRECTLY to out).
//  blocks 32..255 : phase 0 = cooperative W->bf16 transpose-convert (write-
//                   through sc0sc1 + counter gate), then out_proj GEMM
//                   (ni-ownership, flag-gated, reg-dbuf k-loop, nt C-stores).
// ---------------------------------------------------------------------------
__global__ __launch_bounds__(512) void lstm_fused(
    const float* __restrict__ xg,
    const unsigned short* __restrict__ WhT,   // [4][512][512] bf16
    unsigned short* hsbf,                     // [128][64][512] bf16 (poisoned)
    float* __restrict__ outp,                 // out + 8192*10000 (h_t, c_t)
    unsigned short* Wtbf,                     // [10000][512] bf16 (made here)
    const float* __restrict__ Wf,             // W [512][10000] f32
    const float* __restrict__ bias,           // [10000]
    float* __restrict__ Cout,                 // [8192][10000] f32
    unsigned* flags,                          // [128 t][2 G][32 bx] + ctr
    unsigned* wt_ctr)                         // convert-done counter
{
    __shared__ __align__(16) unsigned char smem[41472];
    const int tid = threadIdx.x;

    if (blockIdx.x < NBLK) {
        // =================== SCAN ROLE (R8 + flags) ========================
        unsigned char* hstage = smem;                               // 32KB
        auto P_lds = reinterpret_cast<float (*)[32][17]>(smem + 32768);
        const int bx   = blockIdx.x;
        const int hc0  = bx * 16;
        const int lane = tid & 63, w = tid >> 6;
        const int wm   = w >> 2, wg = w & 3;

        bf16x8 breg[16];
        {
            const unsigned short* base =
                WhT + ((size_t)wg * HIDDEN + hc0 + (lane & 15)) * HIDDEN + (lane >> 4) * 8;
            #pragma unroll
            for (int ks = 0; ks < 16; ++ks)
                breg[ks] = *reinterpret_cast<const bf16x8*>(base + ks * 32);
        }

        const int ub  = tid >> 3;          // 0..31 (tid<256)
        const int uhp = tid & 7;
        const int uhc = hc0 + uhp * 2;
        float cA0 = 0.f, cA1 = 0.f, cB0 = 0.f, cB1 = 0.f;
        f32x2 xvA[4], xvB[4];
        if (tid < 256) {
            const float* xrA = xg + (size_t)(0 * 32 + ub) * NGATE + uhc;
            const float* xrB = xg + (size_t)(1 * 32 + ub) * NGATE + uhc;
            #pragma unroll
            for (int g = 0; g < 4; ++g) {
                xvA[g] = *reinterpret_cast<const f32x2*>(xrA + g * HIDDEN);
                xvB[g] = *reinterpret_cast<const f32x2*>(xrB + g * HIDDEN);
            }
        }
        unsigned* hs32 = reinterpret_cast<unsigned*>(hsbf);

#define CHK(R) { mx = (mx > (unsigned)R[0]) ? mx : (unsigned)R[0]; \
                 mx = (mx > (unsigned)R[1]) ? mx : (unsigned)R[1]; \
                 mx = (mx > (unsigned)R[2]) ? mx : (unsigned)R[2]; \
                 mx = (mx > (unsigned)R[3]) ? mx : (unsigned)R[3]; }
#define STLDS(R, I) { int s16 = (I) * 512 + tid; int row = s16 >> 6, sl = s16 & 63; \
        *reinterpret_cast<i32x4*>(hstage + row * 1024 + ((sl ^ (row & 7)) << 4)) = R; }

#define GROUP_UPDATE(G, XV, C0, C1, TT)                                         \
    if (tid < 256) {                                                            \
        int hp2 = uhp * 2;                                                      \
        float h0, h1;                                                           \
        cell2(P_lds[0][ub][hp2] + XV[0][0], P_lds[0][ub][hp2+1] + XV[0][1],     \
              P_lds[1][ub][hp2] + XV[1][0], P_lds[1][ub][hp2+1] + XV[1][1],     \
              P_lds[2][ub][hp2] + XV[2][0], P_lds[2][ub][hp2+1] + XV[2][1],     \
              P_lds[3][ub][hp2] + XV[3][0], P_lds[3][ub][hp2+1] + XV[3][1],     \
              C0, C1, h0, h1);                                                  \
        unsigned hp = ((unsigned)f32_to_bf16(h1) << 16) | (unsigned)f32_to_bf16(h0); \
        st4ic(hs32 + (size_t)(TT) * 16384 + ((G) * 32 + ub) * 256 + (uhc >> 1), hp); \
        if ((TT) == T_STEPS - 1) {                                              \
            f32x2 hv = { h0, h1 };                                              \
            *reinterpret_cast<f32x2*>(outp + (size_t)((G) * 32 + ub) * HIDDEN + uhc) = hv; \
            f32x2 cv = { C0, C1 };                                              \
            *reinterpret_cast<f32x2*>(outp + 32768 + (size_t)((G) * 32 + ub) * HIDDEN + uhc) = cv; \
        } else {                                                                \
            const float* xr = xg + (size_t)(((TT) + 1) * BATCH + (G) * 32 + ub) * NGATE + uhc; \
            _Pragma("unroll")                                                   \
            for (int g = 0; g < 4; ++g)                                         \
                XV[g] = *reinterpret_cast<const f32x2*>(xr + g * HIDDEN);       \
        }                                                                       \
    }

#define GROUP_PHASE(G, XV, C0, C1, TT)                                          \
    {                                                                           \
        f32x4 acc = {0.f, 0.f, 0.f, 0.f};                                       \
        {                                                                       \
            const char* hb = (const char*)hsbf + (size_t)((TT) - 1) * 65536 + (G) * 32768; \
            i32x4 q0, q1, q2, q3;                                               \
            for (int rnd = 0; rnd < (1 << 16); ++rnd) {                         \
                q0 = ld16ic(hb + (size_t)(0 * 512 + tid) * 16);                 \
                q1 = ld16ic(hb + (size_t)(1 * 512 + tid) * 16);                 \
                q2 = ld16ic(hb + (size_t)(2 * 512 + tid) * 16);                 \
                q3 = ld16ic(hb + (size_t)(3 * 512 + tid) * 16);                 \
                asm volatile("s_waitcnt vmcnt(0)"                               \
                    : "+v"(q0), "+v"(q1), "+v"(q2), "+v"(q3));                  \
                unsigned mx = 0u;                                               \
                CHK(q0) CHK(q1) CHK(q2) CHK(q3)                                 \
                if (mx != 0xFFFFFFFFu) break;                                   \
                __builtin_amdgcn_s_sleep(1);                                    \
            }                                                                   \
            __builtin_amdgcn_sched_barrier(0);                                  \
            STLDS(q0, 0) STLDS(q1, 1) STLDS(q2, 2) STLDS(q3, 3)                 \
        }                                                                       \
        __syncthreads();   /* implied vmcnt(0): prev slot's publishes ACKed */  \
        if (tid == 0) {                                                         \
            int s_ = 2 * (TT) + (G);                                            \
            int ps = s_ - 1;                                                    \
            st4ic(flags + ((size_t)(ps >> 1) * 64 + (ps & 1) * 32 + bx), 1u);   \
            if (s_ == 2) st4ic(flags + bx, 1u);   /* slot 0 = (A,0) */          \
        }                                                                       \
        {                                                                       \
            const int rr = wm * 16 + (lane & 15);                               \
            _Pragma("unroll")                                                   \
            for (int ks = 0; ks < 16; ++ks) {                                   \
                int sl = ks * 4 + (lane >> 4);                                  \
                bf16x8 a = *reinterpret_cast<const bf16x8*>(                    \
                    hstage + rr * 1024 + ((sl ^ (rr & 7)) << 4));               \
                acc = __builtin_amdgcn_mfma_f32_16x16x32_bf16(a, breg[ks], acc, 0, 0, 0); \
            }                                                                   \
        }                                                                       \
        {                                                                       \
            int colr = lane & 15, rowb = (lane >> 4) * 4;                       \
            _Pragma("unroll")                                                   \
            for (int r = 0; r < 4; ++r)                                         \
                P_lds[wg][wm * 16 + rowb + r][colr] = acc[r];                   \
        }                                                                       \
        __syncthreads();                                                        \
        GROUP_UPDATE(G, XV, C0, C1, TT)                                         \
    }

        // t = 0: registers only
        if (tid < 256) {
            float h0, h1;
            cell2(xvA[0][0], xvA[0][1], xvA[1][0], xvA[1][1],
                  xvA[2][0], xvA[2][1], xvA[3][0], xvA[3][1], cA0, cA1, h0, h1);
            unsigned hp = ((unsigned)f32_to_bf16(h1) << 16) | (unsigned)f32_to_bf16(h0);
            st4ic(hs32 + (size_t)(0 * 32 + ub) * 256 + (uhc >> 1), hp);
            const float* xr = xg + (size_t)(1 * BATCH + 0 * 32 + ub) * NGATE + uhc;
            #pragma unroll
            for (int g = 0; g < 4; ++g)
                xvA[g] = *reinterpret_cast<const f32x2*>(xr + g * HIDDEN);

            cell2(xvB[0][0], xvB[0][1], xvB[1][0], xvB[1][1],
                  xvB[2][0], xvB[2][1], xvB[3][0], xvB[3][1], cB0, cB1, h0, h1);
            hp = ((unsigned)f32_to_bf16(h1) << 16) | (unsigned)f32_to_bf16(h0);
            st4ic(hs32 + (size_t)(1 * 32 + ub) * 256 + (uhc >> 1), hp);
            xr = xg + (size_t)(1 * BATCH + 1 * 32 + ub) * NGATE + uhc;
            #pragma unroll
            for (int g = 0; g < 4; ++g)
                xvB[g] = *reinterpret_cast<const f32x2*>(xr + g * HIDDEN);
        }

        for (int t = 1; t < T_STEPS; ++t) {
            GROUP_PHASE(0, xvA, cA0, cA1, t)
            GROUP_PHASE(1, xvB, cB0, cB1, t)
        }
#undef GROUP_PHASE
#undef GROUP_UPDATE
#undef STLDS
#undef CHK
        // final slot (B,127): drain, then fire its flag
        __syncthreads();
        if (tid == 0)
            st4ic(flags + ((size_t)127 * 64 + 32 + bx), 1u);
    } else {
        // ============ GEMM ROLE: phase 0 = W -> Wtbf convert ===============
        const int gbid = blockIdx.x - NBLK;     // 0..223
        const int w = tid >> 6, lane = tid & 63;
        {
            auto tl = reinterpret_cast<float (*)[68]>(smem);   // 64 x 68 f32
            for (int tix = gbid; tix < 157 * 8; tix += NGEMM) {
                int kt = tix / 157, nt_ = tix - kt * 157;
                int n0c = nt_ * 64, k0c = kt * 64;
                #pragma unroll
                for (int i = 0; i < 2; ++i) {
                    int u = tid + i * 512;             // 0..1023
                    int kk = u >> 4, n4 = u & 15;
                    int nn = n0c + n4 * 4;
                    if (nn + 3 < VOCAB) {
                        f32x4 v = *reinterpret_cast<const f32x4*>(
                            Wf + (size_t)(k0c + kk) * VOCAB + nn);
                        *reinterpret_cast<f32x4*>(&tl[kk][n4 * 4]) = v;
                    }
                }
                __syncthreads();
                {
                    int n = tid >> 3, u8 = tid & 7;
                    if (n0c + n < VOCAB) {
                        unsigned short o[8];
                        #pragma unroll
                        for (int j = 0; j < 8; ++j) o[j] = f32_to_bf16(tl[u8 * 8 + j][n]);
                        i32x4 pk;
                        pk[0] = (int)(o[0] | ((unsigned)o[1] << 16));
                        pk[1] = (int)(o[2] | ((unsigned)o[3] << 16));
                        pk[2] = (int)(o[4] | ((unsigned)o[5] << 16));
                        pk[3] = (int)(o[6] | ((unsigned)o[7] << 16));
                        asm volatile("global_store_dwordx4 %0, %1, off sc0 sc1"
                            :: "v"(Wtbf + (size_t)(n0c + n) * HIDDEN + k0c + u8 * 8),
                               "v"(pk) : "memory");
                    }
                }
                __syncthreads();
            }
            asm volatile("s_waitcnt vmcnt(0)" ::: "memory");
            __syncthreads();
            if (tid == 0) {
                __hip_atomic_fetch_add(wt_ctr, 1u, __ATOMIC_RELAXED, __HIP_MEMORY_SCOPE_AGENT);
                for (int rnd = 0; rnd < (1 << 20); ++rnd) {
                    unsigned v = ld4ic(wt_ctr);
                    asm volatile("s_waitcnt vmcnt(0)" : "+v"(v));
                    if (v >= (unsigned)NGEMM) break;
                    __builtin_amdgcn_s_sleep(8);
                }
            }
            __syncthreads();
        }
        // ============ phase 1: drafting out_proj GEMM ======================
        char* sA = (char*)smem;            // 128 rows x 128B = 16KB
        char* sB = (char*)smem + 16384;    // 80 rows x 128B  = 10KB
        const unsigned short* __restrict__ Abf = hsbf;   // read-only here
        const unsigned short* __restrict__ Btbf = Wtbf;

        int ni, mi_lo, mi_hi;
        if (gbid < 99)       { ni = gbid;       mi_lo = 0;  mi_hi = 32; }
        else if (gbid < 125) { ni = gbid;       mi_lo = 0;  mi_hi = 64; }
        else                 { ni = gbid - 125; mi_lo = 32; mi_hi = 64; }
        const int n0 = ni * 80;

        // per-thread staging geometry (fixed across kc)
        const int ar0 = tid >> 3, ar1 = (tid >> 3) + 64, aslot = tid & 7;  // A rows/slot
        const int br0 = tid >> 3, bs0 = tid & 7;                           // B first
        const int br1 = (512 + tid) >> 3, bs1 = tid & 7;                   // B second (tid<128)

        for (int mi = mi_lo; mi < mi_hi; ++mi) {
            int m0 = mi * 128;
            // ---- flag gate: 128 dwords (t = 2mi, 2mi+1; both groups, 32 blks)
            {
                const unsigned* fl = flags + (size_t)2 * mi * 64;
                for (int rnd = 0; rnd < (1 << 20); ++rnd) {
                    unsigned v = 1u;
                    if (tid < 128) v = ld4ic(fl + tid);
                    asm volatile("s_waitcnt vmcnt(0)" : "+v"(v));
                    int bad = (tid < 128) && (v == 0u);
                    if (__syncthreads_count(bad) == 0) break;
                    __builtin_amdgcn_s_sleep(16);
                }
                asm volatile("" ::: "memory");   // keep A loads below the gate
            }
            f32x4 acc[5] = {};
            i32x4 ra0, ra1, rb0, rb1;
            // prologue: issue kc=0 loads (cached; post-flag => safe)
            {
                ra0 = *reinterpret_cast<const i32x4*>(Abf + (size_t)(m0 + ar0) * HIDDEN + aslot * 8);
                ra1 = *reinterpret_cast<const i32x4*>(Abf + (size_t)(m0 + ar1) * HIDDEN + aslot * 8);
                rb0 = *reinterpret_cast<const i32x4*>(Btbf + (size_t)(n0 + br0) * HIDDEN + bs0 * 8);
                if (tid < 128)
                    rb1 = *reinterpret_cast<const i32x4*>(Btbf + (size_t)(n0 + br1) * HIDDEN + bs1 * 8);
            }
            for (int kc = 0; kc < 8; ++kc) {
                *reinterpret_cast<i32x4*>(sA + ar0 * 128 + ((aslot ^ (ar0 & 7)) * 16)) = ra0;
                *reinterpret_cast<i32x4*>(sA + ar1 * 128 + ((aslot ^ (ar1 & 7)) * 16)) = ra1;
                *reinterpret_cast<i32x4*>(sB + br0 * 128 + ((bs0 ^ (br0 & 7)) * 16)) = rb0;
                if (tid < 128)
                    *reinterpret_cast<i32x4*>(sB + br1 * 128 + ((bs1 ^ (br1 & 7)) * 16)) = rb1;
                __syncthreads();
                if (kc < 7) {
                    int k1 = (kc + 1) * 64;
                    ra0 = *reinterpret_cast<const i32x4*>(Abf + (size_t)(m0 + ar0) * HIDDEN + k1 + aslot * 8);
                    ra1 = *reinterpret_cast<const i32x4*>(Abf + (size_t)(m0 + ar1) * HIDDEN + k1 + aslot * 8);
                    rb0 = *reinterpret_cast<const i32x4*>(Btbf + (size_t)(n0 + br0) * HIDDEN + k1 + bs0 * 8);
                    if (tid < 128)
                        rb1 = *reinterpret_cast<const i32x4*>(Btbf + (size_t)(n0 + br1) * HIDDEN + k1 + bs1 * 8);
                }
                #pragma unroll
                for (int k2 = 0; k2 < 2; ++k2) {
                    int arow = w * 16 + (lane & 15);
                    int aoff = (k2 * 64 + (lane >> 4) * 16) ^ ((arow & 7) << 4);
                    bf16x8 a = *reinterpret_cast<const bf16x8*>(sA + arow * 128 + aoff);
                    #pragma unroll
                    for (int cf = 0; cf < 5; ++cf) {
                        int brow = cf * 16 + (lane & 15);
                        int boff = (k2 * 64 + (lane >> 4) * 16) ^ ((brow & 7) << 4);
                        bf16x8 b = *reinterpret_cast<const bf16x8*>(sB + brow * 128 + boff);
                        acc[cf] = __builtin_amdgcn_mfma_f32_16x16x32_bf16(a, b, acc[cf], 0, 0, 0);
                    }
                }
                __syncthreads();
            }
            #pragma unroll
            for (int cf = 0; cf < 5; ++cf) {
                int col = n0 + cf * 16 + (lane & 15);
                float bv = bias[col];
                #pragma unroll
                for (int r = 0; r < 4; ++r) {
                    int row = m0 + w * 16 + (lane >> 4) * 4 + r;
                    st4nt(&Cout[(size_t)row * VOCAB + col], acc[cf][r] + bv);
                }
            }
        }
    }
}

extern "C" void kernel_launch(void* const* d_in, const int* in_sizes, int n_in,
                              void* d_out, int out_size, void* d_ws, size_t ws_size,
                              hipStream_t stream) {
    (void)in_sizes; (void)n_in; (void)out_size; (void)ws_size;
    const int*   input_ = (const int*)  d_in[0];
    const float* Emb    = (const float*)d_in[1];
    const float* Wxi    = (const float*)d_in[2];
    const float* Whi    = (const float*)d_in[3];
    const float* bi     = (const float*)d_in[4];
    const float* Wxf    = (const float*)d_in[5];
    const float* Whf    = (const float*)d_in[6];
    const float* bf_    = (const float*)d_in[7];
    const float* Wxc    = (const float*)d_in[8];
    const float* Whc    = (const float*)d_in[9];
    const float* bc     = (const float*)d_in[10];
    const float* Wxo    = (const float*)d_in[11];
    const float* Who    = (const float*)d_in[12];
    const float* bo     = (const float*)d_in[13];
    const float* W      = (const float*)d_in[14];
    const float* b      = (const float*)d_in[15];
    float* out = (float*)d_out;

    char* ws = (char*)d_ws;
    float*          xg   = (float*)         (ws);                 // 67,108,864
    unsigned short* hsbf = (unsigned short*)(ws +  67108864);     //  8,388,608
    unsigned short* Wtbf = (unsigned short*)(ws +  75497472);     // 10,240,000
    unsigned short* WhT  = (unsigned short*)(ws +  85737472);     //  2,097,152
    unsigned short* Embb = (unsigned short*)(ws +  87834624);     //  5,120,000
    unsigned short* WxT  = (unsigned short*)(ws +  92954624);     //  1,048,576
    unsigned*       flags= (unsigned*)      (ws +  94003200);     //     32,768
    unsigned*       wtc  = (unsigned*)      (ws +  94035968);     //         64

    prep_all<<<2161, 1024, 0, stream>>>(Emb, Embb, (unsigned*)hsbf, flags,
                                        Whi, Whf, Whc, Who, WhT,
                                        Wxi, Wxf, Wxc, Wxo, WxT);
    xproj_mfma<<<dim3(32, 64), 256, 0, stream>>>(input_, Embb, WxT, bi, bf_, bc, bo, xg);

    {
        const float* xg_c = xg;
        const unsigned short* WhT_c = WhT;
        unsigned short* hsbf_p = hsbf;
        float* outp = out + (size_t)M_ROWS * VOCAB;
        unsigned short* Wtbf_p = Wtbf;
        const float* W_c = W;
        const float* b_c = b;
        float* out_p = out;
        unsigned* flags_p = flags;
        unsigned* wtc_p = wtc;
        void* args[] = { (void*)&xg_c, (void*)&WhT_c, (void*)&hsbf_p,
                         (void*)&outp, (void*)&Wtbf_p, (void*)&W_c,
                         (void*)&b_c, (void*)&out_p, (void*)&flags_p, (void*)&wtc_p };
        hipLaunchCooperativeKernel((void*)lstm_fused, dim3(NLAUNCH), dim3(512), args, 0, stream);
    }
}